// Round 1
// baseline (375.296 us; speedup 1.0000x reference)
//
#include <hip/hip_runtime.h>

static constexpr int NWK  = 8192;   // workers
static constexpr int NTK  = 4096;   // tasks
static constexpr int HD   = 128;    // hidden/feature dim
static constexpr int CWW  = 256;    // cap: ww row degree
static constexpr int CWTR = 128;    // cap: wt row degree (per worker)
static constexpr int CWTC = 256;    // cap: wt col degree (per task)

typedef float  f32x4  __attribute__((ext_vector_type(4)));
typedef __bf16 bf16x8 __attribute__((ext_vector_type(8)));

__device__ __forceinline__ float wredmax(float v){
#pragma unroll
  for(int o=32;o;o>>=1) v = fmaxf(v, __shfl_xor(v,o,64));
  return v;
}
__device__ __forceinline__ float wredsum(float v){
#pragma unroll
  for(int o=32;o;o>>=1) v += __shfl_xor(v,o,64);
  return v;
}

// ---- weight prep: W [in][out] f32 -> Wt [out][in] bf16 (B-operand layout)
__global__ __launch_bounds__(256) void prepw(
    const float* s0,const float* s1,const float* s2,const float* s3,
    const float* s4,const float* s5,const float* s6,const float* s7,
    __bf16* dst){
  const float* srcs[8] = {s0,s1,s2,s3,s4,s5,s6,s7};
  const float* s = srcs[blockIdx.x];
  __bf16* d = dst + (size_t)blockIdx.x*HD*HD;
  for(int idx=threadIdx.x; idx<HD*HD; idx+=256){
    int k = idx>>7, n = idx&127;
    d[n*HD+k] = (__bf16)s[idx];
  }
}

// ---- dense adjacency row -> sorted index list (deterministic ballot compaction)
__global__ __launch_bounds__(256) void build_ell(
    const float* __restrict__ adj, int ncols, int cap,
    int* __restrict__ idx, int* __restrict__ deg){
  long row = blockIdx.x;
  const float4* arow = (const float4*)(adj + row*(long)ncols);
  __shared__ int wv[4];
  int t=threadIdx.x, lane=t&63, w=t>>6;
  int base=0;
  int* orow = idx + row*(long)cap;
  for(int it=0; it<ncols; it+=1024){
    float4 v = arow[(it>>2)+t];
    bool p0=v.x>0.f,p1=v.y>0.f,p2=v.z>0.f,p3=v.w>0.f;
    unsigned long long b0=__ballot(p0),b1=__ballot(p1),b2=__ballot(p2),b3=__ballot(p3);
    if(lane==0) wv[w] = __popcll(b0)+__popcll(b1)+__popcll(b2)+__popcll(b3);
    __syncthreads();
    int wbase = base;
    for(int k2=0;k2<w;k2++) wbase += wv[k2];
    unsigned long long below = (1ull<<lane)-1ull;
    int pos = wbase + __popcll(b0&below)+__popcll(b1&below)+__popcll(b2&below)+__popcll(b3&below);
    int c0 = it + t*4;
    if(p0){ if(pos<cap) orow[pos]=c0;   pos++; }
    if(p1){ if(pos<cap) orow[pos]=c0+1; pos++; }
    if(p2){ if(pos<cap) orow[pos]=c0+2; pos++; }
    if(p3){ if(pos<cap) orow[pos]=c0+3; pos++; }
    base += wv[0]+wv[1]+wv[2]+wv[3];
    __syncthreads();
  }
  if(t==0) deg[row] = base<cap ? base : cap;
}

// ---- scatter wt CSR -> wt CSC (per-task worker lists); order nondeterministic, FP-noise only
__global__ __launch_bounds__(128) void scatter_csc(
    const int* __restrict__ widx, const int* __restrict__ wdeg,
    int* __restrict__ cidx, int* __restrict__ fill){
  int wkr = blockIdx.x, t = threadIdx.x;
  if(t < wdeg[wkr]){
    int task = widx[wkr*CWTR + t];
    int p = atomicAdd(&fill[task], 1);
    if(p < CWTC) cidx[task*CWTC + p] = wkr;
  }
}

// ---- fused GEMM: out = [resid +] act(A @ W + bias [+ ex1]),  A:[N,128] f32, Wt:[128out][128in] bf16
__global__ __launch_bounds__(256) void gemm128(
    const float* __restrict__ A, const __bf16* __restrict__ Wt,
    const float* __restrict__ bias, const float* __restrict__ ex1,
    const float* __restrict__ resid, float* __restrict__ out, int act){
  __shared__ __bf16 As[64*HD];           // 16 KB, XOR-swizzled
  char* Ab = (char*)As;
  int t = threadIdx.x, lane = t&63, w = t>>6;
  long r0 = (long)blockIdx.x*64;
  const float4* A4 = (const float4*)(A + r0*HD);
#pragma unroll
  for(int i=0;i<8;i++){
    int id = t + i*256;                  // float4 index in 64x128 tile
    float4 v = A4[id];
    int row = id>>5, c4 = id&31;
    int byte = row*256 + c4*8;
    ushort4 b;
    b.x = __builtin_bit_cast(unsigned short, (__bf16)v.x);
    b.y = __builtin_bit_cast(unsigned short, (__bf16)v.y);
    b.z = __builtin_bit_cast(unsigned short, (__bf16)v.z);
    b.w = __builtin_bit_cast(unsigned short, (__bf16)v.w);
    *(ushort4*)(Ab + (byte ^ ((row&7)<<4))) = b;
  }
  __syncthreads();
  f32x4 acc[4][2] = {};
  int n0 = w*32;
#pragma unroll
  for(int kk=0;kk<4;kk++){
    int kb = kk*32 + (lane>>4)*8;
    bf16x8 bf[2];
#pragma unroll
    for(int n=0;n<2;n++){
      int col = n0 + n*16 + (lane&15);
      bf[n] = *(const bf16x8*)(Wt + col*HD + kb);
    }
#pragma unroll
    for(int m=0;m<4;m++){
      int row = m*16 + (lane&15);
      int byte = row*256 + kb*2;
      bf16x8 af = *(const bf16x8*)(Ab + (byte ^ ((row&7)<<4)));
      acc[m][0] = __builtin_amdgcn_mfma_f32_16x16x32_bf16(af, bf[0], acc[m][0], 0,0,0);
      acc[m][1] = __builtin_amdgcn_mfma_f32_16x16x32_bf16(af, bf[1], acc[m][1], 0,0,0);
    }
  }
#pragma unroll
  for(int m=0;m<4;m++)
#pragma unroll
  for(int n=0;n<2;n++){
    int col = n0 + n*16 + (lane&15);
    float bcol = bias ? bias[col] : 0.f;
#pragma unroll
    for(int i=0;i<4;i++){
      long row = r0 + m*16 + (lane>>4)*4 + i;
      long o = row*HD + col;
      float v = acc[m][n][i] + bcol;
      if(ex1)  v += ex1[o];
      if(act)  v = v>0.f ? v : 0.f;
      if(resid) v += resid[o];
      out[o] = v;
    }
  }
}

// ---- worker messages: msg_w[i] = sum_{j in Nww(i)} Vww[j] + sum_{t in Nwt(i)} Vtw[t]
__global__ __launch_bounds__(256) void agg_w(
    const float* __restrict__ Vww, const float* __restrict__ Vtw,
    const int* __restrict__ wwidx, const int* __restrict__ wwdeg,
    const int* __restrict__ wtidx, const int* __restrict__ wtdeg,
    float* __restrict__ msg){
  int w=threadIdx.x>>6, lane=threadIdx.x&63;
  long i = (long)blockIdx.x*4 + w;
  float ax=0.f, ay=0.f;
  int d = wwdeg[i];
  const int* ji = wwidx + i*CWW;
  for(int k=0;k<d;k++){
    const float2 v = *(const float2*)(Vww + (long)ji[k]*HD + lane*2);
    ax += v.x; ay += v.y;
  }
  d = wtdeg[i];
  ji = wtidx + i*CWTR;
  for(int k=0;k<d;k++){
    const float2 v = *(const float2*)(Vtw + (long)ji[k]*HD + lane*2);
    ax += v.x; ay += v.y;
  }
  float2 o; o.x=ax; o.y=ay;
  *(float2*)(msg + i*HD + lane*2) = o;
}

// ---- task messages: msg_t[t] = sum_{w in CSC(t)} Vwt[w]
__global__ __launch_bounds__(256) void agg_t(
    const float* __restrict__ Vwt, const int* __restrict__ cidx,
    const int* __restrict__ cnt, float* __restrict__ msg){
  int w=threadIdx.x>>6, lane=threadIdx.x&63;
  long i = (long)blockIdx.x*4 + w;
  float ax=0.f, ay=0.f;
  int d = cnt[i]; if(d>CWTC) d=CWTC;
  const int* ji = cidx + i*CWTC;
  for(int k=0;k<d;k++){
    const float2 v = *(const float2*)(Vwt + (long)ji[k]*HD + lane*2);
    ax += v.x; ay += v.y;
  }
  float2 o; o.x=ax; o.y=ay;
  *(float2*)(msg + i*HD + lane*2) = o;
}

// ---- f_src/f_dst + column-sum of Wh (for degree-0 softmax fallback)
__global__ __launch_bounds__(256) void fsrcdst(
    const float* __restrict__ Wh, const float* __restrict__ a_src,
    const float* __restrict__ a_dst, float* __restrict__ fs,
    float* __restrict__ fd, float* __restrict__ whsum){
  int w=threadIdx.x>>6, lane=threadIdx.x&63;
  int wid = blockIdx.x*4 + w;
  int waves = gridDim.x*4;
  float2 as = *(const float2*)(a_src + lane*2);
  float2 ad = *(const float2*)(a_dst + lane*2);
  float cx=0.f, cy=0.f;
  for(int r=wid; r<NWK; r+=waves){
    float2 v = *(const float2*)(Wh + (long)r*HD + lane*2);
    cx += v.x; cy += v.y;
    float s = v.x*as.x + v.y*as.y;
    float d = v.x*ad.x + v.y*ad.y;
    s = wredsum(s); d = wredsum(d);
    if(lane==0){ fs[r]=s; fd[r]=d; }
  }
  atomicAdd(&whsum[lane*2],   cx);
  atomicAdd(&whsum[lane*2+1], cy);
}

// ---- sparse masked attention + ELU + residual -> final_worker
__global__ __launch_bounds__(256) void attn(
    const float* __restrict__ Wh, const float* __restrict__ fs,
    const float* __restrict__ fd, const int* __restrict__ idx,
    const int* __restrict__ deg, const float* __restrict__ h_w,
    const float* __restrict__ whsum, float* __restrict__ out){
  __shared__ float pa[4][CWW];
  int w=threadIdx.x>>6, lane=threadIdx.x&63;
  long i = (long)blockIdx.x*4 + w;
  int d = deg[i];
  const int* ji = idx + i*CWW;
  float ax=0.f, ay=0.f;
  if(d > 0){
    float fsi = fs[i];
    float m = -1e30f;
    for(int k=lane;k<d;k+=64){
      float e = fsi + fd[ji[k]];
      e = e>0.f ? e : 0.2f*e;          // leaky_relu(0.2)
      pa[w][k] = e;
      m = fmaxf(m, e);
    }
    m = wredmax(m);
    float s = 0.f;
    for(int k=lane;k<d;k+=64){
      float e = __expf(pa[w][k]-m);
      pa[w][k] = e;
      s += e;
    }
    s = wredsum(s);
    float inv = 1.f/s;
    for(int k=0;k<d;k++){
      float a = pa[w][k];
      float2 v = *(const float2*)(Wh + (long)ji[k]*HD + lane*2);
      ax += a*v.x; ay += a*v.y;
    }
    ax *= inv; ay *= inv;
  } else {
    ax = whsum[lane*2]   * (1.f/8192.f);   // uniform softmax over all-NEG row
    ay = whsum[lane*2+1] * (1.f/8192.f);
  }
  float2 r = *(const float2*)(h_w + i*HD + lane*2);
  float2 o;
  o.x = (ax>0.f ? ax : __expf(ax)-1.f) + r.x;   // elu + residual
  o.y = (ay>0.f ? ay : __expf(ay)-1.f) + r.y;
  *(float2*)(out + i*HD + lane*2) = o;
}

extern "C" void kernel_launch(void* const* d_in, const int* in_sizes, int n_in,
                              void* d_out, int out_size, void* d_ws, size_t ws_size,
                              hipStream_t stream){
  const float* Xw       = (const float*)d_in[0];
  const float* Xt       = (const float*)d_in[1];
  const float* WW       = (const float*)d_in[2];
  const float* WT       = (const float*)d_in[3];
  const float* Wp_w     = (const float*)d_in[4];
  const float* bp_w     = (const float*)d_in[5];
  const float* Wp_t     = (const float*)d_in[6];
  const float* bp_t     = (const float*)d_in[7];
  const float* W_worker = (const float*)d_in[8];
  const float* b_worker = (const float*)d_in[9];
  const float* W_task   = (const float*)d_in[10];
  const float* b_task   = (const float*)d_in[11];
  const float* W_ww     = (const float*)d_in[12];
  const float* W_wt     = (const float*)d_in[13];
  const float* W_tw     = (const float*)d_in[14];
  const float* W_igat   = (const float*)d_in[15];
  const float* a_src    = (const float*)d_in[16];
  const float* a_dst    = (const float*)d_in[17];
  float* out = (float*)d_out;

  char* p = (char*)d_ws;
  auto alloc = [&](size_t bytes)->char*{
    char* r = p; p += (bytes + 255) & ~(size_t)255; return r;
  };
  int* ww_idx  = (int*)alloc((size_t)NWK*CWW*4);
  int* wt_idx  = (int*)alloc((size_t)NWK*CWTR*4);
  int* wt_cidx = (int*)alloc((size_t)NTK*CWTC*4);
  int* ww_deg  = (int*)alloc(NWK*4);
  int* wt_deg  = (int*)alloc(NWK*4);
  char* zreg   = alloc(NTK*4 + 512);        // fill counters + whsum (one memset)
  int*   fill  = (int*)zreg;
  float* whsum = (float*)(zreg + NTK*4);
  float* h_w   = (float*)alloc((size_t)NWK*HD*4);
  float* h_t   = (float*)alloc((size_t)NTK*HD*4);
  float* Vww   = (float*)alloc((size_t)NWK*HD*4);
  float* Vwt   = (float*)alloc((size_t)NWK*HD*4);
  float* Vtw   = (float*)alloc((size_t)NTK*HD*4);
  float* msg_w = (float*)alloc((size_t)NWK*HD*4);
  float* msg_t = (float*)alloc((size_t)NTK*HD*4);
  float* hwr   = (float*)alloc((size_t)NWK*HD*4);
  float* Wh    = (float*)alloc((size_t)NWK*HD*4);
  float* fs    = (float*)alloc(NWK*4);
  float* fd    = (float*)alloc(NWK*4);
  __bf16* Wtb  = (__bf16*)alloc((size_t)8*HD*HD*2);

  // sparse structure
  prepw<<<8,256,0,stream>>>(Wp_w, Wp_t, W_worker, W_task, W_ww, W_wt, W_tw, W_igat, Wtb);
  build_ell<<<NWK,256,0,stream>>>(WW, NWK, CWW,  ww_idx, ww_deg);
  build_ell<<<NWK,256,0,stream>>>(WT, NTK, CWTR, wt_idx, wt_deg);
  hipMemsetAsync(zreg, 0, NTK*4 + 512, stream);
  scatter_csc<<<NWK,128,0,stream>>>(wt_idx, wt_deg, wt_cidx, fill);

  // projections
  gemm128<<<NWK/64,256,0,stream>>>(Xw, Wtb + 0*HD*HD, bp_w, nullptr, nullptr, h_w, 1);
  gemm128<<<NTK/64,256,0,stream>>>(Xt, Wtb + 1*HD*HD, bp_t, nullptr, nullptr, h_t, 1);

  // per-relation transforms
  gemm128<<<NWK/64,256,0,stream>>>(h_w, Wtb + 4*HD*HD, nullptr, nullptr, nullptr, Vww, 0);
  gemm128<<<NWK/64,256,0,stream>>>(h_w, Wtb + 5*HD*HD, nullptr, nullptr, nullptr, Vwt, 0);
  gemm128<<<NTK/64,256,0,stream>>>(h_t, Wtb + 6*HD*HD, nullptr, nullptr, nullptr, Vtw, 0);

  // sparse aggregation
  agg_w<<<NWK/4,256,0,stream>>>(Vww, Vtw, ww_idx, ww_deg, wt_idx, wt_deg, msg_w);
  agg_t<<<NTK/4,256,0,stream>>>(Vwt, wt_cidx, fill, msg_t);

  // RGCN outputs (final_task fused: relu(...) + h_t -> d_out)
  gemm128<<<NWK/64,256,0,stream>>>(h_w, Wtb + 2*HD*HD, b_worker, msg_w, nullptr, hwr, 1);
  gemm128<<<NTK/64,256,0,stream>>>(h_t, Wtb + 3*HD*HD, b_task,  msg_t, h_t,
                                   out + (size_t)NWK*HD, 1);

  // IGAT
  gemm128<<<NWK/64,256,0,stream>>>(hwr, Wtb + 7*HD*HD, nullptr, nullptr, nullptr, Wh, 0);
  fsrcdst<<<64,256,0,stream>>>(Wh, a_src, a_dst, fs, fd, whsum);
  attn<<<NWK/4,256,0,stream>>>(Wh, fs, fd, ww_idx, ww_deg, h_w, whsum, out);
}

// Round 2
// 271.620 us; speedup vs baseline: 1.3817x; 1.3817x over previous
//
#include <hip/hip_runtime.h>

static constexpr int NWK  = 8192;
static constexpr int NTK  = 4096;
static constexpr int HD   = 128;
static constexpr int CWW  = 256;   // cap ww row degree (mean 82, max~125)
static constexpr int CWTR = 128;   // cap wt row degree (mean 41)
static constexpr int CWTC = 256;   // cap wt col degree (mean 82)

typedef float  f32x4  __attribute__((ext_vector_type(4)));
typedef __bf16 bf16x8 __attribute__((ext_vector_type(8)));

__device__ __forceinline__ float b2f(unsigned short u){
  unsigned int x = ((unsigned int)u) << 16;
  return __builtin_bit_cast(float, x);
}
__device__ __forceinline__ unsigned short f2b(float x){
  return __builtin_bit_cast(unsigned short, (__bf16)x);
}
__device__ __forceinline__ float wredmax(float v){
#pragma unroll
  for(int o=32;o;o>>=1) v = fmaxf(v, __shfl_xor(v,o,64));
  return v;
}
__device__ __forceinline__ float wredsum(float v){
#pragma unroll
  for(int o=32;o;o>>=1) v += __shfl_xor(v,o,64);
  return v;
}

// ---- weight prep: W [in][out] f32 -> Wt [out][in] bf16 ; grid = 8 mats x 4 slices
__global__ __launch_bounds__(256) void prepw(
    const float* s0,const float* s1,const float* s2,const float* s3,
    const float* s4,const float* s5,const float* s6,const float* s7,
    unsigned short* dst){
  const float* srcs[8] = {s0,s1,s2,s3,s4,s5,s6,s7};
  int mat = blockIdx.x>>2, sl = blockIdx.x&3;
  const float* s = srcs[mat];
  unsigned short* d = dst + (size_t)mat*HD*HD;
  for(int idx=threadIdx.x + sl*4096; idx<(sl+1)*4096; idx+=256){
    int k = idx>>7, n = idx&127;
    d[n*HD+k] = f2b(s[idx]);
  }
}

// ---- dense adjacency scan, wave-per-row, sorted compaction; optional fused CSC scatter
__global__ __launch_bounds__(256) void build_ell(
    const float* __restrict__ adj, int ncols, int cap,
    int* __restrict__ idx, int* __restrict__ deg,
    int* __restrict__ cidx, int* __restrict__ fill, int ccap){
  int lane = threadIdx.x&63, w = threadIdx.x>>6;
  int row = blockIdx.x*4 + w;
  const float4* arow = (const float4*)(adj + (long)row*ncols);
  int* orow = idx + (long)row*cap;
  int base = 0;
  int nit = ncols>>8;                 // 256 cols per wave-iter
  for(int it=0; it<nit; it++){
    float4 v = arow[it*64 + lane];
    bool p0=v.x>0.f, p1=v.y>0.f, p2=v.z>0.f, p3=v.w>0.f;
    unsigned long long b0=__ballot(p0),b1=__ballot(p1),b2=__ballot(p2),b3=__ballot(p3);
    unsigned long long below = (1ull<<lane)-1ull;
    int pos = base + __popcll(b0&below)+__popcll(b1&below)+__popcll(b2&below)+__popcll(b3&below);
    int c0 = it*256 + lane*4;
    if(p0){ if(pos<cap){ orow[pos]=c0;
              if(cidx){ int pp=atomicAdd(&fill[c0],1); if(pp<ccap) cidx[(long)c0*ccap+pp]=row; } }
            pos++; }
    if(p1){ if(pos<cap){ orow[pos]=c0+1;
              if(cidx){ int pp=atomicAdd(&fill[c0+1],1); if(pp<ccap) cidx[(long)(c0+1)*ccap+pp]=row; } }
            pos++; }
    if(p2){ if(pos<cap){ orow[pos]=c0+2;
              if(cidx){ int pp=atomicAdd(&fill[c0+2],1); if(pp<ccap) cidx[(long)(c0+2)*ccap+pp]=row; } }
            pos++; }
    if(p3){ if(pos<cap){ orow[pos]=c0+3;
              if(cidx){ int pp=atomicAdd(&fill[c0+3],1); if(pp<ccap) cidx[(long)(c0+3)*ccap+pp]=row; } }
            pos++; }
    base += __popcll(b0)+__popcll(b1)+__popcll(b2)+__popcll(b3);
  }
  if(lane==0) deg[row] = base<cap ? base : cap;
}

// ---- fused projections: h = relu(X@Wp + b), output bf16. blocks [0,256) worker, [256,384) task
__global__ __launch_bounds__(256) void kproj(
    const float* __restrict__ Xw, const float* __restrict__ Xt,
    const unsigned short* __restrict__ Wtb,
    const float* __restrict__ bp_w, const float* __restrict__ bp_t,
    unsigned short* __restrict__ h_w, unsigned short* __restrict__ h_t){
  bool task = blockIdx.x >= (NWK/32);
  const float* X = task ? Xt : Xw;
  const __bf16* Wt = (const __bf16*)(Wtb + (size_t)(task?1:0)*HD*HD);
  const float* bias = task ? bp_t : bp_w;
  unsigned short* H = task ? h_t : h_w;
  long r0 = (long)(task ? blockIdx.x-(NWK/32) : blockIdx.x)*32;

  __shared__ __bf16 As[32*HD];       // 8 KB swizzled
  char* Ab = (char*)As;
  int t = threadIdx.x, lane = t&63, w = t>>6;
  const float4* A4 = (const float4*)(X + r0*HD);
#pragma unroll
  for(int i=0;i<4;i++){
    int id = t + i*256;              // 1024 float4 in 32x128 tile
    float4 v = A4[id];
    int row = id>>5, c4 = id&31;
    int byte = row*256 + c4*8;
    ushort4 b; b.x=f2b(v.x); b.y=f2b(v.y); b.z=f2b(v.z); b.w=f2b(v.w);
    *(ushort4*)(Ab + (byte ^ ((row&7)<<4))) = b;
  }
  __syncthreads();
  f32x4 acc[2][2] = {};
  int n0 = w*32;
#pragma unroll
  for(int kk=0;kk<4;kk++){
    int kb = kk*32 + (lane>>4)*8;
    bf16x8 bf0 = *(const bf16x8*)(Wt + (n0 +      (lane&15))*HD + kb);
    bf16x8 bf1 = *(const bf16x8*)(Wt + (n0 + 16 + (lane&15))*HD + kb);
#pragma unroll
    for(int m=0;m<2;m++){
      int row = m*16 + (lane&15);
      bf16x8 af = *(const bf16x8*)(Ab + ((row*256 + kb*2) ^ ((row&7)<<4)));
      acc[m][0] = __builtin_amdgcn_mfma_f32_16x16x32_bf16(af, bf0, acc[m][0], 0,0,0);
      acc[m][1] = __builtin_amdgcn_mfma_f32_16x16x32_bf16(af, bf1, acc[m][1], 0,0,0);
    }
  }
#pragma unroll
  for(int m=0;m<2;m++)
#pragma unroll
  for(int n=0;n<2;n++){
    int col = n0 + n*16 + (lane&15);
    float bc = bias[col];
#pragma unroll
    for(int i=0;i<4;i++){
      long row = r0 + m*16 + (lane>>4)*4 + i;
      float vv = acc[m][n][i] + bc;
      vv = vv>0.f ? vv : 0.f;
      H[row*HD+col] = f2b(vv);
    }
  }
}

// ---- aggregate raw h: g_ww = ww@h_w, g_tw = wt@h_t (worker rows); g_wt = wt^T@h_w (task rows)
__global__ __launch_bounds__(256) void agg(
    const unsigned short* __restrict__ h_w, const unsigned short* __restrict__ h_t,
    const int* __restrict__ wwidx, const int* __restrict__ wwdeg,
    const int* __restrict__ wtidx, const int* __restrict__ wtdeg,
    const int* __restrict__ cidx,  const int* __restrict__ fill,
    unsigned short* __restrict__ g_ww, unsigned short* __restrict__ g_tw,
    unsigned short* __restrict__ g_wt){
  int w = threadIdx.x>>6, lane = threadIdx.x&63;
  long i = (long)blockIdx.x*4 + w;
  if(i < NWK){
    // g_ww
    float ax=0.f, ay=0.f;
    int d = wwdeg[i];
    const int* ji = wwidx + i*CWW;
    int k=0;
    for(; k+1<d; k+=2){
      long j0=ji[k], j1=ji[k+1];
      ushort2 u0 = *(const ushort2*)(h_w + j0*HD + lane*2);
      ushort2 u1 = *(const ushort2*)(h_w + j1*HD + lane*2);
      ax += b2f(u0.x)+b2f(u1.x); ay += b2f(u0.y)+b2f(u1.y);
    }
    if(k<d){
      long j0=ji[k];
      ushort2 u0 = *(const ushort2*)(h_w + j0*HD + lane*2);
      ax += b2f(u0.x); ay += b2f(u0.y);
    }
    ushort2 o; o.x=f2b(ax); o.y=f2b(ay);
    *(ushort2*)(g_ww + i*HD + lane*2) = o;
    // g_tw
    ax=0.f; ay=0.f;
    d = wtdeg[i];
    ji = wtidx + i*CWTR;
    k=0;
    for(; k+1<d; k+=2){
      long j0=ji[k], j1=ji[k+1];
      ushort2 u0 = *(const ushort2*)(h_t + j0*HD + lane*2);
      ushort2 u1 = *(const ushort2*)(h_t + j1*HD + lane*2);
      ax += b2f(u0.x)+b2f(u1.x); ay += b2f(u0.y)+b2f(u1.y);
    }
    if(k<d){
      long j0=ji[k];
      ushort2 u0 = *(const ushort2*)(h_t + j0*HD + lane*2);
      ax += b2f(u0.x); ay += b2f(u0.y);
    }
    o.x=f2b(ax); o.y=f2b(ay);
    *(ushort2*)(g_tw + i*HD + lane*2) = o;
  } else {
    long tt = i - NWK;
    float ax=0.f, ay=0.f;
    int d = fill[tt]; if(d>CWTC) d=CWTC;
    const int* ji = cidx + tt*CWTC;
    int k=0;
    for(; k+1<d; k+=2){
      long j0=ji[k], j1=ji[k+1];
      ushort2 u0 = *(const ushort2*)(h_w + j0*HD + lane*2);
      ushort2 u1 = *(const ushort2*)(h_w + j1*HD + lane*2);
      ax += b2f(u0.x)+b2f(u1.x); ay += b2f(u0.y)+b2f(u1.y);
    }
    if(k<d){
      long j0=ji[k];
      ushort2 u0 = *(const ushort2*)(h_w + j0*HD + lane*2);
      ax += b2f(u0.x); ay += b2f(u0.y);
    }
    ushort2 o; o.x=f2b(ax); o.y=f2b(ay);
    *(ushort2*)(g_wt + tt*HD + lane*2) = o;
  }
}

// ---- stage a 32x128 bf16 tile into swizzled LDS
__device__ __forceinline__ void stage_bf16(char* Ab, const unsigned short* src, int t){
#pragma unroll
  for(int i=0;i<2;i++){
    int id = t + i*256;              // 512 chunks of 8 bf16
    int row = id>>4, c8 = id&15;
    bf16x8 v = *(const bf16x8*)(src + row*HD + c8*8);
    int byte = row*256 + c8*16;
    *(bf16x8*)(Ab + (byte ^ ((row&7)<<4))) = v;
  }
}

// ---- RGCN + IGAT fused. worker blocks [0,256): hwr = relu(h_w@Ww + g_ww@Www + g_tw@Wtw + b)
//      (LDS only), then Wh = hwr@Wigat (bf16 out) + fs/fd/whsum epilogue.
//      task blocks [256,384): out_task = relu(h_t@Wt + g_wt@Wwt + b) + h_t
__global__ __launch_bounds__(256) void krgcn(
    const unsigned short* __restrict__ h_w, const unsigned short* __restrict__ h_t,
    const unsigned short* __restrict__ g_ww, const unsigned short* __restrict__ g_tw,
    const unsigned short* __restrict__ g_wt,
    const unsigned short* __restrict__ Wtb,
    const float* __restrict__ b_worker, const float* __restrict__ b_task,
    const float* __restrict__ a_src, const float* __restrict__ a_dst,
    unsigned short* __restrict__ Wh, float* __restrict__ fs, float* __restrict__ fd,
    float* __restrict__ whsum, float* __restrict__ out_task){
  __shared__ __bf16 As[3][32*HD];    // 24 KB
  __shared__ __bf16 Hs[32*HD];       // 8 KB
  int t = threadIdx.x, lane = t&63, w = t>>6, n0 = w*32;
  bool task = blockIdx.x >= (NWK/32);

  if(!task){
    long r0 = (long)blockIdx.x*32;
    stage_bf16((char*)As[0], h_w  + r0*HD, t);
    stage_bf16((char*)As[1], g_ww + r0*HD, t);
    stage_bf16((char*)As[2], g_tw + r0*HD, t);
    __syncthreads();
    f32x4 acc[2][2] = {};
    const int slot[3] = {2,4,6};     // W_worker, W_ww, W_tw
#pragma unroll
    for(int s=0;s<3;s++){
      const __bf16* Wt = (const __bf16*)(Wtb + (size_t)slot[s]*HD*HD);
      char* Ab = (char*)As[s];
#pragma unroll
      for(int kk=0;kk<4;kk++){
        int kb = kk*32 + (lane>>4)*8;
        bf16x8 bf0 = *(const bf16x8*)(Wt + (n0 +      (lane&15))*HD + kb);
        bf16x8 bf1 = *(const bf16x8*)(Wt + (n0 + 16 + (lane&15))*HD + kb);
#pragma unroll
        for(int m=0;m<2;m++){
          int row = m*16 + (lane&15);
          bf16x8 af = *(const bf16x8*)(Ab + ((row*256 + kb*2) ^ ((row&7)<<4)));
          acc[m][0] = __builtin_amdgcn_mfma_f32_16x16x32_bf16(af, bf0, acc[m][0], 0,0,0);
          acc[m][1] = __builtin_amdgcn_mfma_f32_16x16x32_bf16(af, bf1, acc[m][1], 0,0,0);
        }
      }
    }
    // bias + relu -> Hs (swizzled bf16)
    char* HsB = (char*)Hs;
#pragma unroll
    for(int m=0;m<2;m++)
#pragma unroll
    for(int n=0;n<2;n++){
      int col = n0 + n*16 + (lane&15);
      float bc = b_worker[col];
#pragma unroll
      for(int i=0;i<4;i++){
        int row = m*16 + (lane>>4)*4 + i;
        float vv = acc[m][n][i] + bc;
        vv = vv>0.f ? vv : 0.f;
        int byte = row*256 + col*2;
        *(__bf16*)(HsB + (byte ^ ((row&7)<<4))) = (__bf16)vv;
      }
    }
    __syncthreads();
    // stage2: Wh = hwr @ W_igat
    f32x4 acc2[2][2] = {};
    const __bf16* Wt7 = (const __bf16*)(Wtb + (size_t)7*HD*HD);
#pragma unroll
    for(int kk=0;kk<4;kk++){
      int kb = kk*32 + (lane>>4)*8;
      bf16x8 bf0 = *(const bf16x8*)(Wt7 + (n0 +      (lane&15))*HD + kb);
      bf16x8 bf1 = *(const bf16x8*)(Wt7 + (n0 + 16 + (lane&15))*HD + kb);
#pragma unroll
      for(int m=0;m<2;m++){
        int row = m*16 + (lane&15);
        bf16x8 af = *(const bf16x8*)(HsB + ((row*256 + kb*2) ^ ((row&7)<<4)));
        acc2[m][0] = __builtin_amdgcn_mfma_f32_16x16x32_bf16(af, bf0, acc2[m][0], 0,0,0);
        acc2[m][1] = __builtin_amdgcn_mfma_f32_16x16x32_bf16(af, bf1, acc2[m][1], 0,0,0);
      }
    }
    // Wh write (bf16)
#pragma unroll
    for(int m=0;m<2;m++)
#pragma unroll
    for(int n=0;n<2;n++){
      int col = n0 + n*16 + (lane&15);
#pragma unroll
      for(int i=0;i<4;i++){
        long row = r0 + m*16 + (lane>>4)*4 + i;
        Wh[row*HD+col] = f2b(acc2[m][n][i]);
      }
    }
    // fs/fd epilogue: fs[r] += sum_c Wh[r][c]*a_src[c] (f32 acc)
    float as0 = a_src[n0 + (lane&15)], as1 = a_src[n0 + 16 + (lane&15)];
    float ad0 = a_dst[n0 + (lane&15)], ad1 = a_dst[n0 + 16 + (lane&15)];
#pragma unroll
    for(int m=0;m<2;m++)
#pragma unroll
    for(int i=0;i<4;i++){
      float ps = acc2[m][0][i]*as0 + acc2[m][1][i]*as1;
      float pd = acc2[m][0][i]*ad0 + acc2[m][1][i]*ad1;
#pragma unroll
      for(int o=1;o<16;o<<=1){ ps += __shfl_xor(ps,o,64); pd += __shfl_xor(pd,o,64); }
      if((lane&15)==0){
        long row = r0 + m*16 + (lane>>4)*4 + i;
        atomicAdd(&fs[row], ps);
        atomicAdd(&fd[row], pd);
      }
    }
    // whsum[c] += column sums (deg-0 softmax fallback)
    float c0=0.f, c1=0.f;
#pragma unroll
    for(int m=0;m<2;m++)
#pragma unroll
    for(int i=0;i<4;i++){ c0 += acc2[m][0][i]; c1 += acc2[m][1][i]; }
    c0 += __shfl_xor(c0,16,64); c0 += __shfl_xor(c0,32,64);
    c1 += __shfl_xor(c1,16,64); c1 += __shfl_xor(c1,32,64);
    if(lane<16){
      atomicAdd(&whsum[n0+lane],    c0);
      atomicAdd(&whsum[n0+16+lane], c1);
    }
  } else {
    long r0 = (long)(blockIdx.x - (NWK/32))*32;
    stage_bf16((char*)As[0], h_t  + r0*HD, t);
    stage_bf16((char*)As[1], g_wt + r0*HD, t);
    __syncthreads();
    f32x4 acc[2][2] = {};
    const int slot[2] = {3,5};       // W_task, W_wt
#pragma unroll
    for(int s=0;s<2;s++){
      const __bf16* Wt = (const __bf16*)(Wtb + (size_t)slot[s]*HD*HD);
      char* Ab = (char*)As[s];
#pragma unroll
      for(int kk=0;kk<4;kk++){
        int kb = kk*32 + (lane>>4)*8;
        bf16x8 bf0 = *(const bf16x8*)(Wt + (n0 +      (lane&15))*HD + kb);
        bf16x8 bf1 = *(const bf16x8*)(Wt + (n0 + 16 + (lane&15))*HD + kb);
#pragma unroll
        for(int m=0;m<2;m++){
          int row = m*16 + (lane&15);
          bf16x8 af = *(const bf16x8*)(Ab + ((row*256 + kb*2) ^ ((row&7)<<4)));
          acc[m][0] = __builtin_amdgcn_mfma_f32_16x16x32_bf16(af, bf0, acc[m][0], 0,0,0);
          acc[m][1] = __builtin_amdgcn_mfma_f32_16x16x32_bf16(af, bf1, acc[m][1], 0,0,0);
        }
      }
    }
#pragma unroll
    for(int m=0;m<2;m++)
#pragma unroll
    for(int n=0;n<2;n++){
      int col = n0 + n*16 + (lane&15);
      float bc = b_task[col];
#pragma unroll
      for(int i=0;i<4;i++){
        long row = r0 + m*16 + (lane>>4)*4 + i;
        float vv = acc[m][n][i] + bc;
        vv = vv>0.f ? vv : 0.f;
        vv += b2f(h_t[row*HD+col]);          // residual
        out_task[row*HD+col] = vv;
      }
    }
  }
}

// ---- sparse masked attention + ELU + residual -> final_worker
__global__ __launch_bounds__(256) void attn(
    const unsigned short* __restrict__ Wh, const float* __restrict__ fs,
    const float* __restrict__ fd, const int* __restrict__ idx,
    const int* __restrict__ deg, const unsigned short* __restrict__ h_w,
    const float* __restrict__ whsum, float* __restrict__ out){
  __shared__ float pa[4][CWW];
  __shared__ int   pj[4][CWW];
  int w = threadIdx.x>>6, lane = threadIdx.x&63;
  long i = (long)blockIdx.x*4 + w;
  int d = deg[i];
  const int* ji = idx + i*CWW;
  float ax=0.f, ay=0.f;
  if(d > 0){
    float fsi = fs[i];
    float m = -1e30f;
    for(int k=lane;k<d;k+=64){
      int j = ji[k]; pj[w][k] = j;
      float e = fsi + fd[j];
      e = e>0.f ? e : 0.2f*e;
      pa[w][k] = e;
      m = fmaxf(m, e);
    }
    m = wredmax(m);
    float ssum = 0.f;
    for(int k=lane;k<d;k+=64){
      float e = __expf(pa[w][k]-m);
      pa[w][k] = e;
      ssum += e;
    }
    ssum = wredsum(ssum);
    float inv = 1.f/ssum;
    int k=0;
    for(; k+1<d; k+=2){
      float a0 = pa[w][k], a1 = pa[w][k+1];
      long j0 = pj[w][k], j1 = pj[w][k+1];
      ushort2 u0 = *(const ushort2*)(Wh + j0*HD + lane*2);
      ushort2 u1 = *(const ushort2*)(Wh + j1*HD + lane*2);
      ax += a0*b2f(u0.x) + a1*b2f(u1.x);
      ay += a0*b2f(u0.y) + a1*b2f(u1.y);
    }
    if(k<d){
      float a0 = pa[w][k];
      long j0 = pj[w][k];
      ushort2 u0 = *(const ushort2*)(Wh + j0*HD + lane*2);
      ax += a0*b2f(u0.x);
      ay += a0*b2f(u0.y);
    }
    ax *= inv; ay *= inv;
  } else {
    ax = whsum[lane*2]   * (1.f/8192.f);
    ay = whsum[lane*2+1] * (1.f/8192.f);
  }
  ushort2 r = *(const ushort2*)(h_w + i*HD + lane*2);
  float2 o;
  o.x = (ax>0.f ? ax : __expf(ax)-1.f) + b2f(r.x);
  o.y = (ay>0.f ? ay : __expf(ay)-1.f) + b2f(r.y);
  *(float2*)(out + i*HD + lane*2) = o;
}

extern "C" void kernel_launch(void* const* d_in, const int* in_sizes, int n_in,
                              void* d_out, int out_size, void* d_ws, size_t ws_size,
                              hipStream_t stream){
  const float* Xw       = (const float*)d_in[0];
  const float* Xt       = (const float*)d_in[1];
  const float* WW       = (const float*)d_in[2];
  const float* WT       = (const float*)d_in[3];
  const float* Wp_w     = (const float*)d_in[4];
  const float* bp_w     = (const float*)d_in[5];
  const float* Wp_t     = (const float*)d_in[6];
  const float* bp_t     = (const float*)d_in[7];
  const float* W_worker = (const float*)d_in[8];
  const float* b_worker = (const float*)d_in[9];
  const float* W_task   = (const float*)d_in[10];
  const float* b_task   = (const float*)d_in[11];
  const float* W_ww     = (const float*)d_in[12];
  const float* W_wt     = (const float*)d_in[13];
  const float* W_tw     = (const float*)d_in[14];
  const float* W_igat   = (const float*)d_in[15];
  const float* a_src    = (const float*)d_in[16];
  const float* a_dst    = (const float*)d_in[17];
  float* out = (float*)d_out;

  char* p = (char*)d_ws;
  auto alloc = [&](size_t bytes)->char*{
    char* r = p; p += (bytes + 255) & ~(size_t)255; return r;
  };
  int* ww_idx  = (int*)alloc((size_t)NWK*CWW*4);
  int* wt_idx  = (int*)alloc((size_t)NWK*CWTR*4);
  int* wt_cidx = (int*)alloc((size_t)NTK*CWTC*4);
  int* ww_deg  = (int*)alloc(NWK*4);
  int* wt_deg  = (int*)alloc(NWK*4);
  // zeroed region: fill | whsum | fs | fd
  size_t ZB = (size_t)NTK*4 + 512 + (size_t)NWK*4 + (size_t)NWK*4;
  char* zreg   = alloc(ZB);
  int*   fill  = (int*)zreg;
  float* whsum = (float*)(zreg + NTK*4);
  float* fs    = (float*)(zreg + NTK*4 + 512);
  float* fd    = (float*)(zreg + NTK*4 + 512 + NWK*4);
  unsigned short* h_w  = (unsigned short*)alloc((size_t)NWK*HD*2);
  unsigned short* h_t  = (unsigned short*)alloc((size_t)NTK*HD*2);
  unsigned short* g_ww = (unsigned short*)alloc((size_t)NWK*HD*2);
  unsigned short* g_tw = (unsigned short*)alloc((size_t)NWK*HD*2);
  unsigned short* g_wt = (unsigned short*)alloc((size_t)NTK*HD*2);
  unsigned short* Wh   = (unsigned short*)alloc((size_t)NWK*HD*2);
  unsigned short* Wtb  = (unsigned short*)alloc((size_t)8*HD*HD*2);

  hipMemsetAsync(zreg, 0, ZB, stream);
  prepw<<<32,256,0,stream>>>(Wp_w, Wp_t, W_worker, W_task, W_ww, W_wt, W_tw, W_igat, Wtb);
  build_ell<<<NWK/4,256,0,stream>>>(WW, NWK, CWW,  ww_idx, ww_deg, nullptr, nullptr, 0);
  build_ell<<<NWK/4,256,0,stream>>>(WT, NTK, CWTR, wt_idx, wt_deg, wt_cidx, fill, CWTC);
  kproj<<<NWK/32 + NTK/32,256,0,stream>>>(Xw, Xt, Wtb, bp_w, bp_t, h_w, h_t);
  agg<<<(NWK+NTK)/4,256,0,stream>>>(h_w, h_t, ww_idx, ww_deg, wt_idx, wt_deg,
                                    wt_cidx, fill, g_ww, g_tw, g_wt);
  krgcn<<<NWK/32 + NTK/32,256,0,stream>>>(h_w, h_t, g_ww, g_tw, g_wt, Wtb,
                                          b_worker, b_task, a_src, a_dst,
                                          Wh, fs, fd, whsum, out + (size_t)NWK*HD);
  attn<<<NWK/4,256,0,stream>>>(Wh, fs, fd, ww_idx, ww_deg, h_w, whsum, out);
}

// Round 3
// 215.874 us; speedup vs baseline: 1.7385x; 1.2582x over previous
//
#include <hip/hip_runtime.h>

static constexpr int NWK  = 8192;
static constexpr int NTK  = 4096;
static constexpr int HD   = 128;
static constexpr int CWW  = 256;   // cap ww row degree (mean 82, max~125)
static constexpr int CWTR = 128;   // cap wt row degree (mean 41)
static constexpr int CWTC = 256;   // cap wt col degree (mean 82)

typedef float  f32x4  __attribute__((ext_vector_type(4)));
typedef __bf16 bf16x8 __attribute__((ext_vector_type(8)));

__device__ __forceinline__ float b2f(unsigned short u){
  unsigned int x = ((unsigned int)u) << 16;
  return __builtin_bit_cast(float, x);
}
__device__ __forceinline__ unsigned short f2b(float x){
  return __builtin_bit_cast(unsigned short, (__bf16)x);
}
__device__ __forceinline__ float wredmax(float v){
#pragma unroll
  for(int o=32;o;o>>=1) v = fmaxf(v, __shfl_xor(v,o,64));
  return v;
}
__device__ __forceinline__ float wredsum(float v){
#pragma unroll
  for(int o=32;o;o>>=1) v += __shfl_xor(v,o,64);
  return v;
}

// ---- weight prep (W [in][out] f32 -> Wt [out][in] bf16) + zero fill/whsum
__global__ __launch_bounds__(256) void prepw(
    const float* s0,const float* s1,const float* s2,const float* s3,
    const float* s4,const float* s5,const float* s6,const float* s7,
    unsigned short* dst, int* fill, float* whsum){
  if(blockIdx.x < 16) fill[blockIdx.x*256 + threadIdx.x] = 0;
  if(blockIdx.x == 16 && threadIdx.x < 128) whsum[threadIdx.x] = 0.f;
  const float* srcs[8] = {s0,s1,s2,s3,s4,s5,s6,s7};
  int mat = blockIdx.x>>2, sl = blockIdx.x&3;
  const float* s = srcs[mat];
  unsigned short* d = dst + (size_t)mat*HD*HD;
  for(int idx=threadIdx.x + sl*4096; idx<(sl+1)*4096; idx+=256){
    int k = idx>>7, n = idx&127;
    d[n*HD+k] = f2b(s[idx]);
  }
}

// ---- dense adjacency scan, wave-per-row, sorted compaction; optional fused CSC scatter
template<bool SCATTER>
__device__ __forceinline__ void scan_row(
    const float* __restrict__ adj, long row, int ncols, int cap,
    int* __restrict__ orow, int* __restrict__ deg,
    int* __restrict__ cidx, int* __restrict__ fill, int ccap, int lane){
  const float4* arow = (const float4*)(adj + row*(long)ncols);
  int base = 0;
  int nit = ncols>>8;                 // 256 cols per wave-iter
  float4 v = arow[lane];
  for(int it=0; it<nit; it++){
    float4 nv = v;
    if(it+1<nit) nv = arow[(it+1)*64 + lane];   // prefetch next chunk
    bool p0=v.x>0.f, p1=v.y>0.f, p2=v.z>0.f, p3=v.w>0.f;
    unsigned long long b0=__ballot(p0),b1=__ballot(p1),b2=__ballot(p2),b3=__ballot(p3);
    unsigned long long below = (1ull<<lane)-1ull;
    int pos = base + __popcll(b0&below)+__popcll(b1&below)+__popcll(b2&below)+__popcll(b3&below);
    int c0 = it*256 + lane*4;
    if(p0){ if(pos<cap){ orow[pos]=c0;
              if(SCATTER){ int pp=atomicAdd(&fill[c0],1); if(pp<ccap) cidx[(long)c0*ccap+pp]=(int)row; } }
            pos++; }
    if(p1){ if(pos<cap){ orow[pos]=c0+1;
              if(SCATTER){ int pp=atomicAdd(&fill[c0+1],1); if(pp<ccap) cidx[(long)(c0+1)*ccap+pp]=(int)row; } }
            pos++; }
    if(p2){ if(pos<cap){ orow[pos]=c0+2;
              if(SCATTER){ int pp=atomicAdd(&fill[c0+2],1); if(pp<ccap) cidx[(long)(c0+2)*ccap+pp]=(int)row; } }
            pos++; }
    if(p3){ if(pos<cap){ orow[pos]=c0+3;
              if(SCATTER){ int pp=atomicAdd(&fill[c0+3],1); if(pp<ccap) cidx[(long)(c0+3)*ccap+pp]=(int)row; } }
            pos++; }
    base += __popcll(b0)+__popcll(b1)+__popcll(b2)+__popcll(b3);
    v = nv;
  }
  if(lane==0) deg[row] = base<cap ? base : cap;
}

__global__ __launch_bounds__(256) void build_all(
    const float* __restrict__ WW, const float* __restrict__ WT,
    int* __restrict__ ww_idx, int* __restrict__ ww_deg,
    int* __restrict__ wt_idx, int* __restrict__ wt_deg,
    int* __restrict__ cidx, int* __restrict__ fill){
  int lane = threadIdx.x&63, w = threadIdx.x>>6;
  int b = blockIdx.x;
  if(b < NWK/4){
    long row = (long)b*4 + w;
    scan_row<false>(WW, row, NWK, CWW, ww_idx + row*CWW, ww_deg, nullptr, nullptr, 0, lane);
  } else {
    long row = (long)(b - NWK/4)*4 + w;
    scan_row<true>(WT, row, NTK, CWTR, wt_idx + row*CWTR, wt_deg, cidx, fill, CWTC, lane);
  }
}

// ---- fused projections: h = relu(X@Wp + b), output bf16
__global__ __launch_bounds__(256) void kproj(
    const float* __restrict__ Xw, const float* __restrict__ Xt,
    const unsigned short* __restrict__ Wtb,
    const float* __restrict__ bp_w, const float* __restrict__ bp_t,
    unsigned short* __restrict__ h_w, unsigned short* __restrict__ h_t){
  bool task = blockIdx.x >= (NWK/32);
  const float* X = task ? Xt : Xw;
  const __bf16* Wt = (const __bf16*)(Wtb + (size_t)(task?1:0)*HD*HD);
  const float* bias = task ? bp_t : bp_w;
  unsigned short* H = task ? h_t : h_w;
  long r0 = (long)(task ? blockIdx.x-(NWK/32) : blockIdx.x)*32;

  __shared__ __bf16 As[32*HD];
  char* Ab = (char*)As;
  int t = threadIdx.x, lane = t&63, w = t>>6;
  const float4* A4 = (const float4*)(X + r0*HD);
#pragma unroll
  for(int i=0;i<4;i++){
    int id = t + i*256;
    float4 v = A4[id];
    int row = id>>5, c4 = id&31;
    int byte = row*256 + c4*8;
    ushort4 b; b.x=f2b(v.x); b.y=f2b(v.y); b.z=f2b(v.z); b.w=f2b(v.w);
    *(ushort4*)(Ab + (byte ^ ((row&7)<<4))) = b;
  }
  __syncthreads();
  f32x4 acc[2][2] = {};
  int n0 = w*32;
#pragma unroll
  for(int kk=0;kk<4;kk++){
    int kb = kk*32 + (lane>>4)*8;
    bf16x8 bf0 = *(const bf16x8*)(Wt + (n0 +      (lane&15))*HD + kb);
    bf16x8 bf1 = *(const bf16x8*)(Wt + (n0 + 16 + (lane&15))*HD + kb);
#pragma unroll
    for(int m=0;m<2;m++){
      int row = m*16 + (lane&15);
      bf16x8 af = *(const bf16x8*)(Ab + ((row*256 + kb*2) ^ ((row&7)<<4)));
      acc[m][0] = __builtin_amdgcn_mfma_f32_16x16x32_bf16(af, bf0, acc[m][0], 0,0,0);
      acc[m][1] = __builtin_amdgcn_mfma_f32_16x16x32_bf16(af, bf1, acc[m][1], 0,0,0);
    }
  }
#pragma unroll
  for(int m=0;m<2;m++)
#pragma unroll
  for(int n=0;n<2;n++){
    int col = n0 + n*16 + (lane&15);
    float bc = bias[col];
#pragma unroll
    for(int i=0;i<4;i++){
      long row = r0 + m*16 + (lane>>4)*4 + i;
      float vv = acc[m][n][i] + bc;
      vv = vv>0.f ? vv : 0.f;
      H[row*HD+col] = f2b(vv);
    }
  }
}

// ---- gather-sum of a bf16 [*,128] table over an index list (4-wide unrolled)
__device__ __forceinline__ void gather_sum(
    const unsigned short* __restrict__ tab, const int* __restrict__ ji, int d,
    int lane, float& ax, float& ay){
  int k=0;
  for(; k+3<d; k+=4){
    long j0=ji[k], j1=ji[k+1], j2=ji[k+2], j3=ji[k+3];
    ushort2 u0 = *(const ushort2*)(tab + j0*HD + lane*2);
    ushort2 u1 = *(const ushort2*)(tab + j1*HD + lane*2);
    ushort2 u2 = *(const ushort2*)(tab + j2*HD + lane*2);
    ushort2 u3 = *(const ushort2*)(tab + j3*HD + lane*2);
    ax += (b2f(u0.x)+b2f(u1.x)) + (b2f(u2.x)+b2f(u3.x));
    ay += (b2f(u0.y)+b2f(u1.y)) + (b2f(u2.y)+b2f(u3.y));
  }
  for(; k<d; ++k){
    long j0=ji[k];
    ushort2 u0 = *(const ushort2*)(tab + j0*HD + lane*2);
    ax += b2f(u0.x); ay += b2f(u0.y);
  }
}

// ---- aggregate raw h
__global__ __launch_bounds__(256) void agg(
    const unsigned short* __restrict__ h_w, const unsigned short* __restrict__ h_t,
    const int* __restrict__ wwidx, const int* __restrict__ wwdeg,
    const int* __restrict__ wtidx, const int* __restrict__ wtdeg,
    const int* __restrict__ cidx,  const int* __restrict__ fill,
    unsigned short* __restrict__ g_ww, unsigned short* __restrict__ g_tw,
    unsigned short* __restrict__ g_wt){
  int w = threadIdx.x>>6, lane = threadIdx.x&63;
  long i = (long)blockIdx.x*4 + w;
  if(i < NWK){
    float ax=0.f, ay=0.f;
    gather_sum(h_w, wwidx + i*CWW, wwdeg[i], lane, ax, ay);
    ushort2 o; o.x=f2b(ax); o.y=f2b(ay);
    *(ushort2*)(g_ww + i*HD + lane*2) = o;
    ax=0.f; ay=0.f;
    gather_sum(h_t, wtidx + i*CWTR, wtdeg[i], lane, ax, ay);
    o.x=f2b(ax); o.y=f2b(ay);
    *(ushort2*)(g_tw + i*HD + lane*2) = o;
  } else {
    long tt = i - NWK;
    float ax=0.f, ay=0.f;
    int d = fill[tt]; if(d>CWTC) d=CWTC;
    gather_sum(h_w, cidx + tt*CWTC, d, lane, ax, ay);
    ushort2 o; o.x=f2b(ax); o.y=f2b(ay);
    *(ushort2*)(g_wt + tt*HD + lane*2) = o;
  }
}

// ---- stage a 32x128 bf16 tile into swizzled LDS
__device__ __forceinline__ void stage_bf16(char* Ab, const unsigned short* src, int t){
#pragma unroll
  for(int i=0;i<2;i++){
    int id = t + i*256;
    int row = id>>4, c8 = id&15;
    bf16x8 v = *(const bf16x8*)(src + row*HD + c8*8);
    int byte = row*256 + c8*16;
    *(bf16x8*)(Ab + (byte ^ ((row&7)<<4))) = v;
  }
}

// ---- RGCN + IGAT fused
__global__ __launch_bounds__(256) void krgcn(
    const unsigned short* __restrict__ h_w, const unsigned short* __restrict__ h_t,
    const unsigned short* __restrict__ g_ww, const unsigned short* __restrict__ g_tw,
    const unsigned short* __restrict__ g_wt,
    const unsigned short* __restrict__ Wtb,
    const float* __restrict__ b_worker, const float* __restrict__ b_task,
    const float* __restrict__ a_src, const float* __restrict__ a_dst,
    unsigned short* __restrict__ Wh, float* __restrict__ fs, float* __restrict__ fd,
    float* __restrict__ whsum, float* __restrict__ out_task){
  __shared__ __bf16 As[3][32*HD];    // 24 KB
  __shared__ __bf16 Hs[32*HD];       // 8 KB
  __shared__ float fsp[32][4], fdp[32][4];
  int t = threadIdx.x, lane = t&63, w = t>>6, n0 = w*32;
  bool task = blockIdx.x >= (NWK/32);

  if(!task){
    long r0 = (long)blockIdx.x*32;
    stage_bf16((char*)As[0], h_w  + r0*HD, t);
    stage_bf16((char*)As[1], g_ww + r0*HD, t);
    stage_bf16((char*)As[2], g_tw + r0*HD, t);
    __syncthreads();
    f32x4 acc[2][2] = {};
    const int slot[3] = {2,4,6};     // W_worker, W_ww, W_tw
#pragma unroll
    for(int s=0;s<3;s++){
      const __bf16* Wt = (const __bf16*)(Wtb + (size_t)slot[s]*HD*HD);
      char* Ab = (char*)As[s];
#pragma unroll
      for(int kk=0;kk<4;kk++){
        int kb = kk*32 + (lane>>4)*8;
        bf16x8 bf0 = *(const bf16x8*)(Wt + (n0 +      (lane&15))*HD + kb);
        bf16x8 bf1 = *(const bf16x8*)(Wt + (n0 + 16 + (lane&15))*HD + kb);
#pragma unroll
        for(int m=0;m<2;m++){
          int row = m*16 + (lane&15);
          bf16x8 af = *(const bf16x8*)(Ab + ((row*256 + kb*2) ^ ((row&7)<<4)));
          acc[m][0] = __builtin_amdgcn_mfma_f32_16x16x32_bf16(af, bf0, acc[m][0], 0,0,0);
          acc[m][1] = __builtin_amdgcn_mfma_f32_16x16x32_bf16(af, bf1, acc[m][1], 0,0,0);
        }
      }
    }
    char* HsB = (char*)Hs;
#pragma unroll
    for(int m=0;m<2;m++)
#pragma unroll
    for(int n=0;n<2;n++){
      int col = n0 + n*16 + (lane&15);
      float bc = b_worker[col];
#pragma unroll
      for(int i=0;i<4;i++){
        int row = m*16 + (lane>>4)*4 + i;
        float vv = acc[m][n][i] + bc;
        vv = vv>0.f ? vv : 0.f;
        int byte = row*256 + col*2;
        *(__bf16*)(HsB + (byte ^ ((row&7)<<4))) = (__bf16)vv;
      }
    }
    __syncthreads();
    // stage2: Wh = hwr @ W_igat
    f32x4 acc2[2][2] = {};
    const __bf16* Wt7 = (const __bf16*)(Wtb + (size_t)7*HD*HD);
#pragma unroll
    for(int kk=0;kk<4;kk++){
      int kb = kk*32 + (lane>>4)*8;
      bf16x8 bf0 = *(const bf16x8*)(Wt7 + (n0 +      (lane&15))*HD + kb);
      bf16x8 bf1 = *(const bf16x8*)(Wt7 + (n0 + 16 + (lane&15))*HD + kb);
#pragma unroll
      for(int m=0;m<2;m++){
        int row = m*16 + (lane&15);
        bf16x8 af = *(const bf16x8*)(HsB + ((row*256 + kb*2) ^ ((row&7)<<4)));
        acc2[m][0] = __builtin_amdgcn_mfma_f32_16x16x32_bf16(af, bf0, acc2[m][0], 0,0,0);
        acc2[m][1] = __builtin_amdgcn_mfma_f32_16x16x32_bf16(af, bf1, acc2[m][1], 0,0,0);
      }
    }
#pragma unroll
    for(int m=0;m<2;m++)
#pragma unroll
    for(int n=0;n<2;n++){
      int col = n0 + n*16 + (lane&15);
#pragma unroll
      for(int i=0;i<4;i++){
        long row = r0 + m*16 + (lane>>4)*4 + i;
        Wh[row*HD+col] = f2b(acc2[m][n][i]);
      }
    }
    // fs/fd: per-wave 32-col partials -> LDS -> block reduce, direct store
    float as0 = a_src[n0 + (lane&15)], as1 = a_src[n0 + 16 + (lane&15)];
    float ad0 = a_dst[n0 + (lane&15)], ad1 = a_dst[n0 + 16 + (lane&15)];
#pragma unroll
    for(int m=0;m<2;m++)
#pragma unroll
    for(int i=0;i<4;i++){
      float ps = acc2[m][0][i]*as0 + acc2[m][1][i]*as1;
      float pd = acc2[m][0][i]*ad0 + acc2[m][1][i]*ad1;
#pragma unroll
      for(int o=1;o<16;o<<=1){ ps += __shfl_xor(ps,o,64); pd += __shfl_xor(pd,o,64); }
      if((lane&15)==0){
        int row = m*16 + (lane>>4)*4 + i;
        fsp[row][w] = ps; fdp[row][w] = pd;
      }
    }
    // whsum column partial (deg-0 fallback)
    float c0=0.f, c1=0.f;
#pragma unroll
    for(int m=0;m<2;m++)
#pragma unroll
    for(int i=0;i<4;i++){ c0 += acc2[m][0][i]; c1 += acc2[m][1][i]; }
    c0 += __shfl_xor(c0,16,64); c0 += __shfl_xor(c0,32,64);
    c1 += __shfl_xor(c1,16,64); c1 += __shfl_xor(c1,32,64);
    if(lane<16){
      atomicAdd(&whsum[n0+lane],    c0);
      atomicAdd(&whsum[n0+16+lane], c1);
    }
    __syncthreads();
    if(t < 32){
      fs[r0+t] = fsp[t][0]+fsp[t][1]+fsp[t][2]+fsp[t][3];
      fd[r0+t] = fdp[t][0]+fdp[t][1]+fdp[t][2]+fdp[t][3];
    }
  } else {
    long r0 = (long)(blockIdx.x - (NWK/32))*32;
    stage_bf16((char*)As[0], h_t  + r0*HD, t);
    stage_bf16((char*)As[1], g_wt + r0*HD, t);
    __syncthreads();
    f32x4 acc[2][2] = {};
    const int slot[2] = {3,5};       // W_task, W_wt
#pragma unroll
    for(int s=0;s<2;s++){
      const __bf16* Wt = (const __bf16*)(Wtb + (size_t)slot[s]*HD*HD);
      char* Ab = (char*)As[s];
#pragma unroll
      for(int kk=0;kk<4;kk++){
        int kb = kk*32 + (lane>>4)*8;
        bf16x8 bf0 = *(const bf16x8*)(Wt + (n0 +      (lane&15))*HD + kb);
        bf16x8 bf1 = *(const bf16x8*)(Wt + (n0 + 16 + (lane&15))*HD + kb);
#pragma unroll
        for(int m=0;m<2;m++){
          int row = m*16 + (lane&15);
          bf16x8 af = *(const bf16x8*)(Ab + ((row*256 + kb*2) ^ ((row&7)<<4)));
          acc[m][0] = __builtin_amdgcn_mfma_f32_16x16x32_bf16(af, bf0, acc[m][0], 0,0,0);
          acc[m][1] = __builtin_amdgcn_mfma_f32_16x16x32_bf16(af, bf1, acc[m][1], 0,0,0);
        }
      }
    }
#pragma unroll
    for(int m=0;m<2;m++)
#pragma unroll
    for(int n=0;n<2;n++){
      int col = n0 + n*16 + (lane&15);
      float bc = b_task[col];
#pragma unroll
      for(int i=0;i<4;i++){
        long row = r0 + m*16 + (lane>>4)*4 + i;
        float vv = acc[m][n][i] + bc;
        vv = vv>0.f ? vv : 0.f;
        vv += b2f(h_t[row*HD+col]);
        out_task[row*HD+col] = vv;
      }
    }
  }
}

// ---- sparse masked attention + ELU + residual -> final_worker
__global__ __launch_bounds__(256) void attn(
    const unsigned short* __restrict__ Wh, const float* __restrict__ fs,
    const float* __restrict__ fd, const int* __restrict__ idx,
    const int* __restrict__ deg, const unsigned short* __restrict__ h_w,
    const float* __restrict__ whsum, float* __restrict__ out){
  __shared__ float pa[4][CWW];
  __shared__ int   pj[4][CWW];
  int w = threadIdx.x>>6, lane = threadIdx.x&63;
  long i = (long)blockIdx.x*4 + w;
  int d = deg[i];
  const int* ji = idx + i*CWW;
  float ax=0.f, ay=0.f;
  if(d > 0){
    float fsi = fs[i];
    float m = -1e30f;
    for(int k=lane;k<d;k+=64){
      int j = ji[k]; pj[w][k] = j;
      float e = fsi + fd[j];
      e = e>0.f ? e : 0.2f*e;
      pa[w][k] = e;
      m = fmaxf(m, e);
    }
    m = wredmax(m);
    float ssum = 0.f;
    for(int k=lane;k<d;k+=64){
      float e = __expf(pa[w][k]-m);
      pa[w][k] = e;
      ssum += e;
    }
    ssum = wredsum(ssum);
    float inv = 1.f/ssum;
    int k=0;
    for(; k+3<d; k+=4){
      float a0=pa[w][k], a1=pa[w][k+1], a2=pa[w][k+2], a3=pa[w][k+3];
      long j0=pj[w][k], j1=pj[w][k+1], j2=pj[w][k+2], j3=pj[w][k+3];
      ushort2 u0 = *(const ushort2*)(Wh + j0*HD + lane*2);
      ushort2 u1 = *(const ushort2*)(Wh + j1*HD + lane*2);
      ushort2 u2 = *(const ushort2*)(Wh + j2*HD + lane*2);
      ushort2 u3 = *(const ushort2*)(Wh + j3*HD + lane*2);
      ax += (a0*b2f(u0.x) + a1*b2f(u1.x)) + (a2*b2f(u2.x) + a3*b2f(u3.x));
      ay += (a0*b2f(u0.y) + a1*b2f(u1.y)) + (a2*b2f(u2.y) + a3*b2f(u3.y));
    }
    for(; k<d; ++k){
      float a0 = pa[w][k];
      long j0 = pj[w][k];
      ushort2 u0 = *(const ushort2*)(Wh + j0*HD + lane*2);
      ax += a0*b2f(u0.x);
      ay += a0*b2f(u0.y);
    }
    ax *= inv; ay *= inv;
  } else {
    ax = whsum[lane*2]   * (1.f/8192.f);
    ay = whsum[lane*2+1] * (1.f/8192.f);
  }
  ushort2 r = *(const ushort2*)(h_w + i*HD + lane*2);
  float2 o;
  o.x = (ax>0.f ? ax : __expf(ax)-1.f) + b2f(r.x);
  o.y = (ay>0.f ? ay : __expf(ay)-1.f) + b2f(r.y);
  *(float2*)(out + i*HD + lane*2) = o;
}

extern "C" void kernel_launch(void* const* d_in, const int* in_sizes, int n_in,
                              void* d_out, int out_size, void* d_ws, size_t ws_size,
                              hipStream_t stream){
  const float* Xw       = (const float*)d_in[0];
  const float* Xt       = (const float*)d_in[1];
  const float* WW       = (const float*)d_in[2];
  const float* WT       = (const float*)d_in[3];
  const float* Wp_w     = (const float*)d_in[4];
  const float* bp_w     = (const float*)d_in[5];
  const float* Wp_t     = (const float*)d_in[6];
  const float* bp_t     = (const float*)d_in[7];
  const float* W_worker = (const float*)d_in[8];
  const float* b_worker = (const float*)d_in[9];
  const float* W_task   = (const float*)d_in[10];
  const float* b_task   = (const float*)d_in[11];
  const float* W_ww     = (const float*)d_in[12];
  const float* W_wt     = (const float*)d_in[13];
  const float* W_tw     = (const float*)d_in[14];
  const float* W_igat   = (const float*)d_in[15];
  const float* a_src    = (const float*)d_in[16];
  const float* a_dst    = (const float*)d_in[17];
  float* out = (float*)d_out;

  char* p = (char*)d_ws;
  auto alloc = [&](size_t bytes)->char*{
    char* r = p; p += (bytes + 255) & ~(size_t)255; return r;
  };
  int* ww_idx  = (int*)alloc((size_t)NWK*CWW*4);
  int* wt_idx  = (int*)alloc((size_t)NWK*CWTR*4);
  int* wt_cidx = (int*)alloc((size_t)NTK*CWTC*4);
  int* ww_deg  = (int*)alloc(NWK*4);
  int* wt_deg  = (int*)alloc(NWK*4);
  int*   fill  = (int*)alloc(NTK*4);
  float* whsum = (float*)alloc(512);
  float* fs    = (float*)alloc(NWK*4);
  float* fd    = (float*)alloc(NWK*4);
  unsigned short* h_w  = (unsigned short*)alloc((size_t)NWK*HD*2);
  unsigned short* h_t  = (unsigned short*)alloc((size_t)NTK*HD*2);
  unsigned short* g_ww = (unsigned short*)alloc((size_t)NWK*HD*2);
  unsigned short* g_tw = (unsigned short*)alloc((size_t)NWK*HD*2);
  unsigned short* g_wt = (unsigned short*)alloc((size_t)NTK*HD*2);
  unsigned short* Wh   = (unsigned short*)alloc((size_t)NWK*HD*2);
  unsigned short* Wtb  = (unsigned short*)alloc((size_t)8*HD*HD*2);

  prepw<<<32,256,0,stream>>>(Wp_w, Wp_t, W_worker, W_task, W_ww, W_wt, W_tw, W_igat,
                             Wtb, fill, whsum);
  build_all<<<NWK/2,256,0,stream>>>(WW, WT, ww_idx, ww_deg, wt_idx, wt_deg, wt_cidx, fill);
  kproj<<<NWK/32 + NTK/32,256,0,stream>>>(Xw, Xt, Wtb, bp_w, bp_t, h_w, h_t);
  agg<<<(NWK+NTK)/4,256,0,stream>>>(h_w, h_t, ww_idx, ww_deg, wt_idx, wt_deg,
                                    wt_cidx, fill, g_ww, g_tw, g_wt);
  krgcn<<<NWK/32 + NTK/32,256,0,stream>>>(h_w, h_t, g_ww, g_tw, g_wt, Wtb,
                                          b_worker, b_task, a_src, a_dst,
                                          Wh, fs, fd, whsum, out + (size_t)NWK*HD);
  attn<<<NWK/4,256,0,stream>>>(Wh, fs, fd, ww_idx, ww_deg, h_w, whsum, out);
}

// Round 4
// 200.750 us; speedup vs baseline: 1.8695x; 1.0753x over previous
//
#include <hip/hip_runtime.h>

static constexpr int NWK  = 8192;
static constexpr int NTK  = 4096;
static constexpr int HD   = 128;
static constexpr int CWW  = 256;   // cap ww row degree (mean 82, max~125)
static constexpr int CWTR = 128;   // cap wt row degree (mean 41)
static constexpr int CWTC = 256;   // cap wt col degree (mean 82)

typedef float  f32x4  __attribute__((ext_vector_type(4)));
typedef __bf16 bf16x8 __attribute__((ext_vector_type(8)));

__device__ __forceinline__ float b2f(unsigned short u){
  unsigned int x = ((unsigned int)u) << 16;
  return __builtin_bit_cast(float, x);
}
__device__ __forceinline__ unsigned short f2b(float x){
  return __builtin_bit_cast(unsigned short, (__bf16)x);
}
__device__ __forceinline__ float wredmax(float v){
#pragma unroll
  for(int o=32;o;o>>=1) v = fmaxf(v, __shfl_xor(v,o,64));
  return v;
}
__device__ __forceinline__ float wredsum(float v){
#pragma unroll
  for(int o=32;o;o>>=1) v += __shfl_xor(v,o,64);
  return v;
}

// ---- weight prep (W [in][out] f32 -> Wt [out][in] bf16) + zero fill/whsum
__global__ __launch_bounds__(256) void prepw(
    const float* s0,const float* s1,const float* s2,const float* s3,
    const float* s4,const float* s5,const float* s6,const float* s7,
    unsigned short* dst, int* fill, float* whsum){
  if(blockIdx.x < 16) fill[blockIdx.x*256 + threadIdx.x] = 0;
  if(blockIdx.x == 16 && threadIdx.x < 128) whsum[threadIdx.x] = 0.f;
  const float* srcs[8] = {s0,s1,s2,s3,s4,s5,s6,s7};
  int mat = blockIdx.x>>2, sl = blockIdx.x&3;
  const float* s = srcs[mat];
  unsigned short* d = dst + (size_t)mat*HD*HD;
  for(int idx=threadIdx.x + sl*4096; idx<(sl+1)*4096; idx+=256){
    int k = idx>>7, n = idx&127;
    d[n*HD+k] = f2b(s[idx]);
  }
}

// ---- process one 256-col chunk: ballot compaction (+ optional CSC scatter)
template<bool SCATTER>
__device__ __forceinline__ void scan_chunk(
    float4 x, int c0base, int& base, int cap,
    int* __restrict__ orow, int* __restrict__ cidx, int* __restrict__ fill,
    int ccap, int lane, long row){
  bool p0=x.x>0.f, p1=x.y>0.f, p2=x.z>0.f, p3=x.w>0.f;
  unsigned long long b0=__ballot(p0),b1=__ballot(p1),b2=__ballot(p2),b3=__ballot(p3);
  unsigned long long below = (1ull<<lane)-1ull;
  int pos = base + __popcll(b0&below)+__popcll(b1&below)+__popcll(b2&below)+__popcll(b3&below);
  int c0 = c0base + lane*4;
  if(p0){ if(pos<cap){ orow[pos]=c0;
            if(SCATTER){ int pp=atomicAdd(&fill[c0],1); if(pp<ccap) cidx[(long)c0*ccap+pp]=(int)row; } }
          pos++; }
  if(p1){ if(pos<cap){ orow[pos]=c0+1;
            if(SCATTER){ int pp=atomicAdd(&fill[c0+1],1); if(pp<ccap) cidx[(long)(c0+1)*ccap+pp]=(int)row; } }
          pos++; }
  if(p2){ if(pos<cap){ orow[pos]=c0+2;
            if(SCATTER){ int pp=atomicAdd(&fill[c0+2],1); if(pp<ccap) cidx[(long)(c0+2)*ccap+pp]=(int)row; } }
          pos++; }
  if(p3){ if(pos<cap){ orow[pos]=c0+3;
            if(SCATTER){ int pp=atomicAdd(&fill[c0+3],1); if(pp<ccap) cidx[(long)(c0+3)*ccap+pp]=(int)row; } }
          pos++; }
  base += __popcll(b0)+__popcll(b1)+__popcll(b2)+__popcll(b3);
}

// ---- dense adjacency scan, wave-per-row, 4-deep load batching + prefetch
template<bool SCATTER>
__device__ __forceinline__ void scan_row(
    const float* __restrict__ adj, long row, int ncols, int cap,
    int* __restrict__ orow, int* __restrict__ deg,
    int* __restrict__ cidx, int* __restrict__ fill, int ccap, int lane){
  const float4* arow = (const float4*)(adj + row*(long)ncols);
  int base = 0;
  const int nit = ncols>>10;          // 1024 cols (4 chunks of 256) per iter
  float4 v[4], nv[4];
#pragma unroll
  for(int c=0;c<4;c++) v[c] = arow[c*64 + lane];
  for(int it=0; it<nit; it++){
    if(it+1<nit){
#pragma unroll
      for(int c=0;c<4;c++) nv[c] = arow[(it+1)*256 + c*64 + lane];
    }
#pragma unroll
    for(int c=0;c<4;c++)
      scan_chunk<SCATTER>(v[c], it*1024 + c*256, base, cap, orow, cidx, fill, ccap, lane, row);
#pragma unroll
    for(int c=0;c<4;c++) v[c] = nv[c];
  }
  if(lane==0) deg[row] = base<cap ? base : cap;
}

__global__ __launch_bounds__(256) void build_all(
    const float* __restrict__ WW, const float* __restrict__ WT,
    int* __restrict__ ww_idx, int* __restrict__ ww_deg,
    int* __restrict__ wt_idx, int* __restrict__ wt_deg,
    int* __restrict__ cidx, int* __restrict__ fill){
  int lane = threadIdx.x&63, w = threadIdx.x>>6;
  int b = blockIdx.x;
  if(b < NWK/4){
    long row = (long)b*4 + w;
    scan_row<false>(WW, row, NWK, CWW, ww_idx + row*CWW, ww_deg, nullptr, nullptr, 0, lane);
  } else {
    long row = (long)(b - NWK/4)*4 + w;
    scan_row<true>(WT, row, NTK, CWTR, wt_idx + row*CWTR, wt_deg, cidx, fill, CWTC, lane);
  }
}

// ---- fused projections: h = relu(X@Wp + b), output bf16
__global__ __launch_bounds__(256) void kproj(
    const float* __restrict__ Xw, const float* __restrict__ Xt,
    const unsigned short* __restrict__ Wtb,
    const float* __restrict__ bp_w, const float* __restrict__ bp_t,
    unsigned short* __restrict__ h_w, unsigned short* __restrict__ h_t){
  bool task = blockIdx.x >= (NWK/32);
  const float* X = task ? Xt : Xw;
  const __bf16* Wt = (const __bf16*)(Wtb + (size_t)(task?1:0)*HD*HD);
  const float* bias = task ? bp_t : bp_w;
  unsigned short* H = task ? h_t : h_w;
  long r0 = (long)(task ? blockIdx.x-(NWK/32) : blockIdx.x)*32;

  __shared__ __bf16 As[32*HD];
  char* Ab = (char*)As;
  int t = threadIdx.x, lane = t&63, w = t>>6;
  const float4* A4 = (const float4*)(X + r0*HD);
#pragma unroll
  for(int i=0;i<4;i++){
    int id = t + i*256;
    float4 v = A4[id];
    int row = id>>5, c4 = id&31;
    int byte = row*256 + c4*8;
    ushort4 b; b.x=f2b(v.x); b.y=f2b(v.y); b.z=f2b(v.z); b.w=f2b(v.w);
    *(ushort4*)(Ab + (byte ^ ((row&7)<<4))) = b;
  }
  __syncthreads();
  f32x4 acc[2][2] = {};
  int n0 = w*32;
#pragma unroll
  for(int kk=0;kk<4;kk++){
    int kb = kk*32 + (lane>>4)*8;
    bf16x8 bf0 = *(const bf16x8*)(Wt + (n0 +      (lane&15))*HD + kb);
    bf16x8 bf1 = *(const bf16x8*)(Wt + (n0 + 16 + (lane&15))*HD + kb);
#pragma unroll
    for(int m=0;m<2;m++){
      int row = m*16 + (lane&15);
      bf16x8 af = *(const bf16x8*)(Ab + ((row*256 + kb*2) ^ ((row&7)<<4)));
      acc[m][0] = __builtin_amdgcn_mfma_f32_16x16x32_bf16(af, bf0, acc[m][0], 0,0,0);
      acc[m][1] = __builtin_amdgcn_mfma_f32_16x16x32_bf16(af, bf1, acc[m][1], 0,0,0);
    }
  }
#pragma unroll
  for(int m=0;m<2;m++)
#pragma unroll
  for(int n=0;n<2;n++){
    int col = n0 + n*16 + (lane&15);
    float bc = bias[col];
#pragma unroll
    for(int i=0;i<4;i++){
      long row = r0 + m*16 + (lane>>4)*4 + i;
      float vv = acc[m][n][i] + bc;
      vv = vv>0.f ? vv : 0.f;
      H[row*HD+col] = f2b(vv);
    }
  }
}

// ---- gather-sum of a bf16 [*,128] table over an index list (4-wide unrolled)
__device__ __forceinline__ void gather_sum(
    const unsigned short* __restrict__ tab, const int* __restrict__ ji, int d,
    int lane, float& ax, float& ay){
  int k=0;
  for(; k+3<d; k+=4){
    long j0=ji[k], j1=ji[k+1], j2=ji[k+2], j3=ji[k+3];
    ushort2 u0 = *(const ushort2*)(tab + j0*HD + lane*2);
    ushort2 u1 = *(const ushort2*)(tab + j1*HD + lane*2);
    ushort2 u2 = *(const ushort2*)(tab + j2*HD + lane*2);
    ushort2 u3 = *(const ushort2*)(tab + j3*HD + lane*2);
    ax += (b2f(u0.x)+b2f(u1.x)) + (b2f(u2.x)+b2f(u3.x));
    ay += (b2f(u0.y)+b2f(u1.y)) + (b2f(u2.y)+b2f(u3.y));
  }
  for(; k<d; ++k){
    long j0=ji[k];
    ushort2 u0 = *(const ushort2*)(tab + j0*HD + lane*2);
    ax += b2f(u0.x); ay += b2f(u0.y);
  }
}

// ---- aggregate raw h
__global__ __launch_bounds__(256) void agg(
    const unsigned short* __restrict__ h_w, const unsigned short* __restrict__ h_t,
    const int* __restrict__ wwidx, const int* __restrict__ wwdeg,
    const int* __restrict__ wtidx, const int* __restrict__ wtdeg,
    const int* __restrict__ cidx,  const int* __restrict__ fill,
    unsigned short* __restrict__ g_ww, unsigned short* __restrict__ g_tw,
    unsigned short* __restrict__ g_wt){
  int w = threadIdx.x>>6, lane = threadIdx.x&63;
  long i = (long)blockIdx.x*4 + w;
  if(i < NWK){
    float ax=0.f, ay=0.f;
    gather_sum(h_w, wwidx + i*CWW, wwdeg[i], lane, ax, ay);
    ushort2 o; o.x=f2b(ax); o.y=f2b(ay);
    *(ushort2*)(g_ww + i*HD + lane*2) = o;
    ax=0.f; ay=0.f;
    gather_sum(h_t, wtidx + i*CWTR, wtdeg[i], lane, ax, ay);
    o.x=f2b(ax); o.y=f2b(ay);
    *(ushort2*)(g_tw + i*HD + lane*2) = o;
  } else {
    long tt = i - NWK;
    float ax=0.f, ay=0.f;
    int d = fill[tt]; if(d>CWTC) d=CWTC;
    gather_sum(h_w, cidx + tt*CWTC, d, lane, ax, ay);
    ushort2 o; o.x=f2b(ax); o.y=f2b(ay);
    *(ushort2*)(g_wt + tt*HD + lane*2) = o;
  }
}

// ---- stage a 32x128 bf16 tile into swizzled LDS
__device__ __forceinline__ void stage_bf16(char* Ab, const unsigned short* src, int t){
#pragma unroll
  for(int i=0;i<2;i++){
    int id = t + i*256;
    int row = id>>4, c8 = id&15;
    bf16x8 v = *(const bf16x8*)(src + row*HD + c8*8);
    int byte = row*256 + c8*16;
    *(bf16x8*)(Ab + (byte ^ ((row&7)<<4))) = v;
  }
}

// ---- RGCN + IGAT fused
__global__ __launch_bounds__(256) void krgcn(
    const unsigned short* __restrict__ h_w, const unsigned short* __restrict__ h_t,
    const unsigned short* __restrict__ g_ww, const unsigned short* __restrict__ g_tw,
    const unsigned short* __restrict__ g_wt,
    const unsigned short* __restrict__ Wtb,
    const float* __restrict__ b_worker, const float* __restrict__ b_task,
    const float* __restrict__ a_src, const float* __restrict__ a_dst,
    unsigned short* __restrict__ Wh, float* __restrict__ fs, float* __restrict__ fd,
    float* __restrict__ whsum, float* __restrict__ out_task){
  __shared__ __bf16 As[3][32*HD];    // 24 KB
  __shared__ __bf16 Hs[32*HD];       // 8 KB
  __shared__ float fsp[32][4], fdp[32][4];
  int t = threadIdx.x, lane = t&63, w = t>>6, n0 = w*32;
  bool task = blockIdx.x >= (NWK/32);

  if(!task){
    long r0 = (long)blockIdx.x*32;
    stage_bf16((char*)As[0], h_w  + r0*HD, t);
    stage_bf16((char*)As[1], g_ww + r0*HD, t);
    stage_bf16((char*)As[2], g_tw + r0*HD, t);
    __syncthreads();
    f32x4 acc[2][2] = {};
    const int slot[3] = {2,4,6};     // W_worker, W_ww, W_tw
#pragma unroll
    for(int s=0;s<3;s++){
      const __bf16* Wt = (const __bf16*)(Wtb + (size_t)slot[s]*HD*HD);
      char* Ab = (char*)As[s];
#pragma unroll
      for(int kk=0;kk<4;kk++){
        int kb = kk*32 + (lane>>4)*8;
        bf16x8 bf0 = *(const bf16x8*)(Wt + (n0 +      (lane&15))*HD + kb);
        bf16x8 bf1 = *(const bf16x8*)(Wt + (n0 + 16 + (lane&15))*HD + kb);
#pragma unroll
        for(int m=0;m<2;m++){
          int row = m*16 + (lane&15);
          bf16x8 af = *(const bf16x8*)(Ab + ((row*256 + kb*2) ^ ((row&7)<<4)));
          acc[m][0] = __builtin_amdgcn_mfma_f32_16x16x32_bf16(af, bf0, acc[m][0], 0,0,0);
          acc[m][1] = __builtin_amdgcn_mfma_f32_16x16x32_bf16(af, bf1, acc[m][1], 0,0,0);
        }
      }
    }
    char* HsB = (char*)Hs;
#pragma unroll
    for(int m=0;m<2;m++)
#pragma unroll
    for(int n=0;n<2;n++){
      int col = n0 + n*16 + (lane&15);
      float bc = b_worker[col];
#pragma unroll
      for(int i=0;i<4;i++){
        int row = m*16 + (lane>>4)*4 + i;
        float vv = acc[m][n][i] + bc;
        vv = vv>0.f ? vv : 0.f;
        int byte = row*256 + col*2;
        *(__bf16*)(HsB + (byte ^ ((row&7)<<4))) = (__bf16)vv;
      }
    }
    __syncthreads();
    // stage2: Wh = hwr @ W_igat
    f32x4 acc2[2][2] = {};
    const __bf16* Wt7 = (const __bf16*)(Wtb + (size_t)7*HD*HD);
#pragma unroll
    for(int kk=0;kk<4;kk++){
      int kb = kk*32 + (lane>>4)*8;
      bf16x8 bf0 = *(const bf16x8*)(Wt7 + (n0 +      (lane&15))*HD + kb);
      bf16x8 bf1 = *(const bf16x8*)(Wt7 + (n0 + 16 + (lane&15))*HD + kb);
#pragma unroll
      for(int m=0;m<2;m++){
        int row = m*16 + (lane&15);
        bf16x8 af = *(const bf16x8*)(HsB + ((row*256 + kb*2) ^ ((row&7)<<4)));
        acc2[m][0] = __builtin_amdgcn_mfma_f32_16x16x32_bf16(af, bf0, acc2[m][0], 0,0,0);
        acc2[m][1] = __builtin_amdgcn_mfma_f32_16x16x32_bf16(af, bf1, acc2[m][1], 0,0,0);
      }
    }
#pragma unroll
    for(int m=0;m<2;m++)
#pragma unroll
    for(int n=0;n<2;n++){
      int col = n0 + n*16 + (lane&15);
#pragma unroll
      for(int i=0;i<4;i++){
        long row = r0 + m*16 + (lane>>4)*4 + i;
        Wh[row*HD+col] = f2b(acc2[m][n][i]);
      }
    }
    // fs/fd: per-wave 32-col partials -> LDS -> block reduce, direct store
    float as0 = a_src[n0 + (lane&15)], as1 = a_src[n0 + 16 + (lane&15)];
    float ad0 = a_dst[n0 + (lane&15)], ad1 = a_dst[n0 + 16 + (lane&15)];
#pragma unroll
    for(int m=0;m<2;m++)
#pragma unroll
    for(int i=0;i<4;i++){
      float ps = acc2[m][0][i]*as0 + acc2[m][1][i]*as1;
      float pd = acc2[m][0][i]*ad0 + acc2[m][1][i]*ad1;
#pragma unroll
      for(int o=1;o<16;o<<=1){ ps += __shfl_xor(ps,o,64); pd += __shfl_xor(pd,o,64); }
      if((lane&15)==0){
        int row = m*16 + (lane>>4)*4 + i;
        fsp[row][w] = ps; fdp[row][w] = pd;
      }
    }
    // whsum column partial (deg-0 fallback)
    float c0=0.f, c1=0.f;
#pragma unroll
    for(int m=0;m<2;m++)
#pragma unroll
    for(int i=0;i<4;i++){ c0 += acc2[m][0][i]; c1 += acc2[m][1][i]; }
    c0 += __shfl_xor(c0,16,64); c0 += __shfl_xor(c0,32,64);
    c1 += __shfl_xor(c1,16,64); c1 += __shfl_xor(c1,32,64);
    if(lane<16){
      atomicAdd(&whsum[n0+lane],    c0);
      atomicAdd(&whsum[n0+16+lane], c1);
    }
    __syncthreads();
    if(t < 32){
      fs[r0+t] = fsp[t][0]+fsp[t][1]+fsp[t][2]+fsp[t][3];
      fd[r0+t] = fdp[t][0]+fdp[t][1]+fdp[t][2]+fdp[t][3];
    }
  } else {
    long r0 = (long)(blockIdx.x - (NWK/32))*32;
    stage_bf16((char*)As[0], h_t  + r0*HD, t);
    stage_bf16((char*)As[1], g_wt + r0*HD, t);
    __syncthreads();
    f32x4 acc[2][2] = {};
    const int slot[2] = {3,5};       // W_task, W_wt
#pragma unroll
    for(int s=0;s<2;s++){
      const __bf16* Wt = (const __bf16*)(Wtb + (size_t)slot[s]*HD*HD);
      char* Ab = (char*)As[s];
#pragma unroll
      for(int kk=0;kk<4;kk++){
        int kb = kk*32 + (lane>>4)*8;
        bf16x8 bf0 = *(const bf16x8*)(Wt + (n0 +      (lane&15))*HD + kb);
        bf16x8 bf1 = *(const bf16x8*)(Wt + (n0 + 16 + (lane&15))*HD + kb);
#pragma unroll
        for(int m=0;m<2;m++){
          int row = m*16 + (lane&15);
          bf16x8 af = *(const bf16x8*)(Ab + ((row*256 + kb*2) ^ ((row&7)<<4)));
          acc[m][0] = __builtin_amdgcn_mfma_f32_16x16x32_bf16(af, bf0, acc[m][0], 0,0,0);
          acc[m][1] = __builtin_amdgcn_mfma_f32_16x16x32_bf16(af, bf1, acc[m][1], 0,0,0);
        }
      }
    }
#pragma unroll
    for(int m=0;m<2;m++)
#pragma unroll
    for(int n=0;n<2;n++){
      int col = n0 + n*16 + (lane&15);
      float bc = b_task[col];
#pragma unroll
      for(int i=0;i<4;i++){
        long row = r0 + m*16 + (lane>>4)*4 + i;
        float vv = acc[m][n][i] + bc;
        vv = vv>0.f ? vv : 0.f;
        vv += b2f(h_t[row*HD+col]);
        out_task[row*HD+col] = vv;
      }
    }
  }
}

// ---- sparse masked attention + ELU + residual -> final_worker
__global__ __launch_bounds__(256) void attn(
    const unsigned short* __restrict__ Wh, const float* __restrict__ fs,
    const float* __restrict__ fd, const int* __restrict__ idx,
    const int* __restrict__ deg, const unsigned short* __restrict__ h_w,
    const float* __restrict__ whsum, float* __restrict__ out){
  __shared__ float pa[4][CWW];
  __shared__ int   pj[4][CWW];
  int w = threadIdx.x>>6, lane = threadIdx.x&63;
  long i = (long)blockIdx.x*4 + w;
  int d = deg[i];
  const int* ji = idx + i*CWW;
  float ax=0.f, ay=0.f;
  if(d > 0){
    float fsi = fs[i];
    float m = -1e30f;
    for(int k=lane;k<d;k+=64){
      int j = ji[k]; pj[w][k] = j;
      float e = fsi + fd[j];
      e = e>0.f ? e : 0.2f*e;
      pa[w][k] = e;
      m = fmaxf(m, e);
    }
    m = wredmax(m);
    float ssum = 0.f;
    for(int k=lane;k<d;k+=64){
      float e = __expf(pa[w][k]-m);
      pa[w][k] = e;
      ssum += e;
    }
    ssum = wredsum(ssum);
    float inv = 1.f/ssum;
    int k=0;
    for(; k+3<d; k+=4){
      float a0=pa[w][k], a1=pa[w][k+1], a2=pa[w][k+2], a3=pa[w][k+3];
      long j0=pj[w][k], j1=pj[w][k+1], j2=pj[w][k+2], j3=pj[w][k+3];
      ushort2 u0 = *(const ushort2*)(Wh + j0*HD + lane*2);
      ushort2 u1 = *(const ushort2*)(Wh + j1*HD + lane*2);
      ushort2 u2 = *(const ushort2*)(Wh + j2*HD + lane*2);
      ushort2 u3 = *(const ushort2*)(Wh + j3*HD + lane*2);
      ax += (a0*b2f(u0.x) + a1*b2f(u1.x)) + (a2*b2f(u2.x) + a3*b2f(u3.x));
      ay += (a0*b2f(u0.y) + a1*b2f(u1.y)) + (a2*b2f(u2.y) + a3*b2f(u3.y));
    }
    for(; k<d; ++k){
      float a0 = pa[w][k];
      long j0 = pj[w][k];
      ushort2 u0 = *(const ushort2*)(Wh + j0*HD + lane*2);
      ax += a0*b2f(u0.x);
      ay += a0*b2f(u0.y);
    }
    ax *= inv; ay *= inv;
  } else {
    ax = whsum[lane*2]   * (1.f/8192.f);
    ay = whsum[lane*2+1] * (1.f/8192.f);
  }
  ushort2 r = *(const ushort2*)(h_w + i*HD + lane*2);
  float2 o;
  o.x = (ax>0.f ? ax : __expf(ax)-1.f) + b2f(r.x);
  o.y = (ay>0.f ? ay : __expf(ay)-1.f) + b2f(r.y);
  *(float2*)(out + i*HD + lane*2) = o;
}

extern "C" void kernel_launch(void* const* d_in, const int* in_sizes, int n_in,
                              void* d_out, int out_size, void* d_ws, size_t ws_size,
                              hipStream_t stream){
  const float* Xw       = (const float*)d_in[0];
  const float* Xt       = (const float*)d_in[1];
  const float* WW       = (const float*)d_in[2];
  const float* WT       = (const float*)d_in[3];
  const float* Wp_w     = (const float*)d_in[4];
  const float* bp_w     = (const float*)d_in[5];
  const float* Wp_t     = (const float*)d_in[6];
  const float* bp_t     = (const float*)d_in[7];
  const float* W_worker = (const float*)d_in[8];
  const float* b_worker = (const float*)d_in[9];
  const float* W_task   = (const float*)d_in[10];
  const float* b_task   = (const float*)d_in[11];
  const float* W_ww     = (const float*)d_in[12];
  const float* W_wt     = (const float*)d_in[13];
  const float* W_tw     = (const float*)d_in[14];
  const float* W_igat   = (const float*)d_in[15];
  const float* a_src    = (const float*)d_in[16];
  const float* a_dst    = (const float*)d_in[17];
  float* out = (float*)d_out;

  char* p = (char*)d_ws;
  auto alloc = [&](size_t bytes)->char*{
    char* r = p; p += (bytes + 255) & ~(size_t)255; return r;
  };
  int* ww_idx  = (int*)alloc((size_t)NWK*CWW*4);
  int* wt_idx  = (int*)alloc((size_t)NWK*CWTR*4);
  int* wt_cidx = (int*)alloc((size_t)NTK*CWTC*4);
  int* ww_deg  = (int*)alloc(NWK*4);
  int* wt_deg  = (int*)alloc(NWK*4);
  int*   fill  = (int*)alloc(NTK*4);
  float* whsum = (float*)alloc(512);
  float* fs    = (float*)alloc(NWK*4);
  float* fd    = (float*)alloc(NWK*4);
  unsigned short* h_w  = (unsigned short*)alloc((size_t)NWK*HD*2);
  unsigned short* h_t  = (unsigned short*)alloc((size_t)NTK*HD*2);
  unsigned short* g_ww = (unsigned short*)alloc((size_t)NWK*HD*2);
  unsigned short* g_tw = (unsigned short*)alloc((size_t)NWK*HD*2);
  unsigned short* g_wt = (unsigned short*)alloc((size_t)NTK*HD*2);
  unsigned short* Wh   = (unsigned short*)alloc((size_t)NWK*HD*2);
  unsigned short* Wtb  = (unsigned short*)alloc((size_t)8*HD*HD*2);

  prepw<<<32,256,0,stream>>>(Wp_w, Wp_t, W_worker, W_task, W_ww, W_wt, W_tw, W_igat,
                             Wtb, fill, whsum);
  build_all<<<NWK/2,256,0,stream>>>(WW, WT, ww_idx, ww_deg, wt_idx, wt_deg, wt_cidx, fill);
  kproj<<<NWK/32 + NTK/32,256,0,stream>>>(Xw, Xt, Wtb, bp_w, bp_t, h_w, h_t);
  agg<<<(NWK+NTK)/4,256,0,stream>>>(h_w, h_t, ww_idx, ww_deg, wt_idx, wt_deg,
                                    wt_cidx, fill, g_ww, g_tw, g_wt);
  krgcn<<<NWK/32 + NTK/32,256,0,stream>>>(h_w, h_t, g_ww, g_tw, g_wt, Wtb,
                                          b_worker, b_task, a_src, a_dst,
                                          Wh, fs, fd, whsum, out + (size_t)NWK*HD);
  attn<<<NWK/4,256,0,stream>>>(Wh, fs, fd, ww_idx, ww_deg, h_w, whsum, out);
}

// Round 5
// 172.486 us; speedup vs baseline: 2.1758x; 1.1639x over previous
//
#include <hip/hip_runtime.h>

static constexpr int NWK  = 8192;
static constexpr int NTK  = 4096;
static constexpr int HD   = 128;
static constexpr int CWW  = 256;   // cap ww row degree (mean 82, max~125)
static constexpr int CWTR = 128;   // cap wt row degree (mean 41)
static constexpr int CWTC = 256;   // cap wt col degree (mean 82)

typedef float  f32x4  __attribute__((ext_vector_type(4)));
typedef __bf16 bf16x8 __attribute__((ext_vector_type(8)));

__device__ __forceinline__ float b2f(unsigned short u){
  unsigned int x = ((unsigned int)u) << 16;
  return __builtin_bit_cast(float, x);
}
__device__ __forceinline__ unsigned short f2b(float x){
  return __builtin_bit_cast(unsigned short, (__bf16)x);
}
__device__ __forceinline__ float wredmax(float v){
#pragma unroll
  for(int o=32;o;o>>=1) v = fmaxf(v, __shfl_xor(v,o,64));
  return v;
}
__device__ __forceinline__ float wredsum(float v){
#pragma unroll
  for(int o=32;o;o>>=1) v += __shfl_xor(v,o,64);
  return v;
}

// ---- weight prep (W [in][out] f32 -> Wt [out][in] bf16) + zero fill/whsum
__global__ __launch_bounds__(256) void prepw(
    const float* s0,const float* s1,const float* s2,const float* s3,
    const float* s4,const float* s5,const float* s6,const float* s7,
    unsigned short* dst, int* fill, float* whsum){
  if(blockIdx.x < 16) fill[blockIdx.x*256 + threadIdx.x] = 0;
  if(blockIdx.x == 16 && threadIdx.x < 128) whsum[threadIdx.x] = 0.f;
  const float* srcs[8] = {s0,s1,s2,s3,s4,s5,s6,s7};
  int mat = blockIdx.x>>2, sl = blockIdx.x&3;
  const float* s = srcs[mat];
  unsigned short* d = dst + (size_t)mat*HD*HD;
  for(int idx=threadIdx.x + sl*4096; idx<(sl+1)*4096; idx+=256){
    int k = idx>>7, n = idx&127;
    d[n*HD+k] = f2b(s[idx]);
  }
}

// ---- one 256-col chunk: ballot compaction into LDS (no VMEM writes!)
template<int CAP>
__device__ __forceinline__ void scan_chunk(
    float4 x, int c0base, int& base, int* __restrict__ sbuf, int lane){
  bool p0=x.x>0.f, p1=x.y>0.f, p2=x.z>0.f, p3=x.w>0.f;
  unsigned long long b0=__ballot(p0),b1=__ballot(p1),b2=__ballot(p2),b3=__ballot(p3);
  unsigned long long below = (1ull<<lane)-1ull;
  int pos = base + __popcll(b0&below)+__popcll(b1&below)+__popcll(b2&below)+__popcll(b3&below);
  int c0 = c0base + lane*4;
  if(p0){ if(pos<CAP) sbuf[pos]=c0;   pos++; }
  if(p1){ if(pos<CAP) sbuf[pos]=c0+1; pos++; }
  if(p2){ if(pos<CAP) sbuf[pos]=c0+2; pos++; }
  if(p3){ if(pos<CAP) sbuf[pos]=c0+3; pos++; }
  base += __popcll(b0)+__popcll(b1)+__popcll(b2)+__popcll(b3);
}

// ---- wave-per-row scan: loads + LDS compaction in loop; coalesced dump + scatter at end
template<bool SCATTER, int CAP>
__device__ __forceinline__ void scan_row(
    const float* __restrict__ adj, long row, int ncols,
    int* __restrict__ orow, int* __restrict__ deg,
    int* __restrict__ cidx, int* __restrict__ fill, int ccap,
    int lane, int* __restrict__ sbuf){
  const float4* arow = (const float4*)(adj + row*(long)ncols);
  int base = 0;
  const int nit = ncols>>10;          // 1024 cols (4 chunks of 256) per iter
  float4 v[4], nv[4];
#pragma unroll
  for(int c=0;c<4;c++) v[c] = arow[c*64 + lane];
  for(int it=0; it<nit-1; it++){
#pragma unroll
    for(int c=0;c<4;c++) nv[c] = arow[(it+1)*256 + c*64 + lane];   // unconditional prefetch
#pragma unroll
    for(int c=0;c<4;c++)
      scan_chunk<CAP>(v[c], it*1024 + c*256, base, sbuf, lane);
#pragma unroll
    for(int c=0;c<4;c++) v[c] = nv[c];
  }
#pragma unroll
  for(int c=0;c<4;c++)                 // peeled last iteration
    scan_chunk<CAP>(v[c], (nit-1)*1024 + c*256, base, sbuf, lane);

  int d = base<CAP ? base : CAP;
  if(lane==0) deg[row] = d;
  // coalesced dump of the whole capacity (entries >= d never read downstream)
  if(CAP == 256){
    int4 q = ((const int4*)sbuf)[lane];
    ((int4*)orow)[lane] = q;
  } else {
    int2 q = ((const int2*)sbuf)[lane];
    ((int2*)orow)[lane] = q;
  }
  if(SCATTER){
    for(int k=lane; k<d; k+=64){
      int task = sbuf[k];
      int pp = atomicAdd(&fill[task], 1);
      if(pp < ccap) cidx[(long)task*ccap + pp] = (int)row;
    }
  }
}

__global__ __launch_bounds__(256) void build_all(
    const float* __restrict__ WW, const float* __restrict__ WT,
    int* __restrict__ ww_idx, int* __restrict__ ww_deg,
    int* __restrict__ wt_idx, int* __restrict__ wt_deg,
    int* __restrict__ cidx, int* __restrict__ fill){
  __shared__ int sbuf[4][CWW];       // 4 KB: per-wave compaction buffer
  int lane = threadIdx.x&63, w = threadIdx.x>>6;
  int b = blockIdx.x;
  if(b < NWK/4){
    long row = (long)b*4 + w;
    scan_row<false,CWW>(WW, row, NWK, ww_idx + row*CWW, ww_deg,
                        nullptr, nullptr, 0, lane, sbuf[w]);
  } else {
    long row = (long)(b - NWK/4)*4 + w;
    scan_row<true,CWTR>(WT, row, NTK, wt_idx + row*CWTR, wt_deg,
                        cidx, fill, CWTC, lane, sbuf[w]);
  }
}

// ---- fused projections: h = relu(X@Wp + b), output bf16
__global__ __launch_bounds__(256) void kproj(
    const float* __restrict__ Xw, const float* __restrict__ Xt,
    const unsigned short* __restrict__ Wtb,
    const float* __restrict__ bp_w, const float* __restrict__ bp_t,
    unsigned short* __restrict__ h_w, unsigned short* __restrict__ h_t){
  bool task = blockIdx.x >= (NWK/32);
  const float* X = task ? Xt : Xw;
  const __bf16* Wt = (const __bf16*)(Wtb + (size_t)(task?1:0)*HD*HD);
  const float* bias = task ? bp_t : bp_w;
  unsigned short* H = task ? h_t : h_w;
  long r0 = (long)(task ? blockIdx.x-(NWK/32) : blockIdx.x)*32;

  __shared__ __bf16 As[32*HD];
  char* Ab = (char*)As;
  int t = threadIdx.x, lane = t&63, w = t>>6;
  const float4* A4 = (const float4*)(X + r0*HD);
#pragma unroll
  for(int i=0;i<4;i++){
    int id = t + i*256;
    float4 v = A4[id];
    int row = id>>5, c4 = id&31;
    int byte = row*256 + c4*8;
    ushort4 b; b.x=f2b(v.x); b.y=f2b(v.y); b.z=f2b(v.z); b.w=f2b(v.w);
    *(ushort4*)(Ab + (byte ^ ((row&7)<<4))) = b;
  }
  __syncthreads();
  f32x4 acc[2][2] = {};
  int n0 = w*32;
#pragma unroll
  for(int kk=0;kk<4;kk++){
    int kb = kk*32 + (lane>>4)*8;
    bf16x8 bf0 = *(const bf16x8*)(Wt + (n0 +      (lane&15))*HD + kb);
    bf16x8 bf1 = *(const bf16x8*)(Wt + (n0 + 16 + (lane&15))*HD + kb);
#pragma unroll
    for(int m=0;m<2;m++){
      int row = m*16 + (lane&15);
      bf16x8 af = *(const bf16x8*)(Ab + ((row*256 + kb*2) ^ ((row&7)<<4)));
      acc[m][0] = __builtin_amdgcn_mfma_f32_16x16x32_bf16(af, bf0, acc[m][0], 0,0,0);
      acc[m][1] = __builtin_amdgcn_mfma_f32_16x16x32_bf16(af, bf1, acc[m][1], 0,0,0);
    }
  }
#pragma unroll
  for(int m=0;m<2;m++)
#pragma unroll
  for(int n=0;n<2;n++){
    int col = n0 + n*16 + (lane&15);
    float bc = bias[col];
#pragma unroll
    for(int i=0;i<4;i++){
      long row = r0 + m*16 + (lane>>4)*4 + i;
      float vv = acc[m][n][i] + bc;
      vv = vv>0.f ? vv : 0.f;
      H[row*HD+col] = f2b(vv);
    }
  }
}

// ---- gather-sum of a bf16 [*,128] table over an index list (4-wide unrolled)
__device__ __forceinline__ void gather_sum(
    const unsigned short* __restrict__ tab, const int* __restrict__ ji, int d,
    int lane, float& ax, float& ay){
  int k=0;
  for(; k+3<d; k+=4){
    long j0=ji[k], j1=ji[k+1], j2=ji[k+2], j3=ji[k+3];
    ushort2 u0 = *(const ushort2*)(tab + j0*HD + lane*2);
    ushort2 u1 = *(const ushort2*)(tab + j1*HD + lane*2);
    ushort2 u2 = *(const ushort2*)(tab + j2*HD + lane*2);
    ushort2 u3 = *(const ushort2*)(tab + j3*HD + lane*2);
    ax += (b2f(u0.x)+b2f(u1.x)) + (b2f(u2.x)+b2f(u3.x));
    ay += (b2f(u0.y)+b2f(u1.y)) + (b2f(u2.y)+b2f(u3.y));
  }
  for(; k<d; ++k){
    long j0=ji[k];
    ushort2 u0 = *(const ushort2*)(tab + j0*HD + lane*2);
    ax += b2f(u0.x); ay += b2f(u0.y);
  }
}

// ---- aggregate raw h
__global__ __launch_bounds__(256) void agg(
    const unsigned short* __restrict__ h_w, const unsigned short* __restrict__ h_t,
    const int* __restrict__ wwidx, const int* __restrict__ wwdeg,
    const int* __restrict__ wtidx, const int* __restrict__ wtdeg,
    const int* __restrict__ cidx,  const int* __restrict__ fill,
    unsigned short* __restrict__ g_ww, unsigned short* __restrict__ g_tw,
    unsigned short* __restrict__ g_wt){
  int w = threadIdx.x>>6, lane = threadIdx.x&63;
  long i = (long)blockIdx.x*4 + w;
  if(i < NWK){
    float ax=0.f, ay=0.f;
    gather_sum(h_w, wwidx + i*CWW, wwdeg[i], lane, ax, ay);
    ushort2 o; o.x=f2b(ax); o.y=f2b(ay);
    *(ushort2*)(g_ww + i*HD + lane*2) = o;
    ax=0.f; ay=0.f;
    gather_sum(h_t, wtidx + i*CWTR, wtdeg[i], lane, ax, ay);
    o.x=f2b(ax); o.y=f2b(ay);
    *(ushort2*)(g_tw + i*HD + lane*2) = o;
  } else {
    long tt = i - NWK;
    float ax=0.f, ay=0.f;
    int d = fill[tt]; if(d>CWTC) d=CWTC;
    gather_sum(h_w, cidx + tt*CWTC, d, lane, ax, ay);
    ushort2 o; o.x=f2b(ax); o.y=f2b(ay);
    *(ushort2*)(g_wt + tt*HD + lane*2) = o;
  }
}

// ---- stage a 32x128 bf16 tile into swizzled LDS
__device__ __forceinline__ void stage_bf16(char* Ab, const unsigned short* src, int t){
#pragma unroll
  for(int i=0;i<2;i++){
    int id = t + i*256;
    int row = id>>4, c8 = id&15;
    bf16x8 v = *(const bf16x8*)(src + row*HD + c8*8);
    int byte = row*256 + c8*16;
    *(bf16x8*)(Ab + (byte ^ ((row&7)<<4))) = v;
  }
}

// ---- RGCN + IGAT fused
__global__ __launch_bounds__(256) void krgcn(
    const unsigned short* __restrict__ h_w, const unsigned short* __restrict__ h_t,
    const unsigned short* __restrict__ g_ww, const unsigned short* __restrict__ g_tw,
    const unsigned short* __restrict__ g_wt,
    const unsigned short* __restrict__ Wtb,
    const float* __restrict__ b_worker, const float* __restrict__ b_task,
    const float* __restrict__ a_src, const float* __restrict__ a_dst,
    unsigned short* __restrict__ Wh, float* __restrict__ fs, float* __restrict__ fd,
    float* __restrict__ whsum, float* __restrict__ out_task){
  __shared__ __bf16 As[3][32*HD];    // 24 KB
  __shared__ __bf16 Hs[32*HD];       // 8 KB
  __shared__ float fsp[32][4], fdp[32][4];
  int t = threadIdx.x, lane = t&63, w = t>>6, n0 = w*32;
  bool task = blockIdx.x >= (NWK/32);

  if(!task){
    long r0 = (long)blockIdx.x*32;
    stage_bf16((char*)As[0], h_w  + r0*HD, t);
    stage_bf16((char*)As[1], g_ww + r0*HD, t);
    stage_bf16((char*)As[2], g_tw + r0*HD, t);
    __syncthreads();
    f32x4 acc[2][2] = {};
    const int slot[3] = {2,4,6};     // W_worker, W_ww, W_tw
#pragma unroll
    for(int s=0;s<3;s++){
      const __bf16* Wt = (const __bf16*)(Wtb + (size_t)slot[s]*HD*HD);
      char* Ab = (char*)As[s];
#pragma unroll
      for(int kk=0;kk<4;kk++){
        int kb = kk*32 + (lane>>4)*8;
        bf16x8 bf0 = *(const bf16x8*)(Wt + (n0 +      (lane&15))*HD + kb);
        bf16x8 bf1 = *(const bf16x8*)(Wt + (n0 + 16 + (lane&15))*HD + kb);
#pragma unroll
        for(int m=0;m<2;m++){
          int row = m*16 + (lane&15);
          bf16x8 af = *(const bf16x8*)(Ab + ((row*256 + kb*2) ^ ((row&7)<<4)));
          acc[m][0] = __builtin_amdgcn_mfma_f32_16x16x32_bf16(af, bf0, acc[m][0], 0,0,0);
          acc[m][1] = __builtin_amdgcn_mfma_f32_16x16x32_bf16(af, bf1, acc[m][1], 0,0,0);
        }
      }
    }
    char* HsB = (char*)Hs;
#pragma unroll
    for(int m=0;m<2;m++)
#pragma unroll
    for(int n=0;n<2;n++){
      int col = n0 + n*16 + (lane&15);
      float bc = b_worker[col];
#pragma unroll
      for(int i=0;i<4;i++){
        int row = m*16 + (lane>>4)*4 + i;
        float vv = acc[m][n][i] + bc;
        vv = vv>0.f ? vv : 0.f;
        int byte = row*256 + col*2;
        *(__bf16*)(HsB + (byte ^ ((row&7)<<4))) = (__bf16)vv;
      }
    }
    __syncthreads();
    // stage2: Wh = hwr @ W_igat
    f32x4 acc2[2][2] = {};
    const __bf16* Wt7 = (const __bf16*)(Wtb + (size_t)7*HD*HD);
#pragma unroll
    for(int kk=0;kk<4;kk++){
      int kb = kk*32 + (lane>>4)*8;
      bf16x8 bf0 = *(const bf16x8*)(Wt7 + (n0 +      (lane&15))*HD + kb);
      bf16x8 bf1 = *(const bf16x8*)(Wt7 + (n0 + 16 + (lane&15))*HD + kb);
#pragma unroll
      for(int m=0;m<2;m++){
        int row = m*16 + (lane&15);
        bf16x8 af = *(const bf16x8*)(HsB + ((row*256 + kb*2) ^ ((row&7)<<4)));
        acc2[m][0] = __builtin_amdgcn_mfma_f32_16x16x32_bf16(af, bf0, acc2[m][0], 0,0,0);
        acc2[m][1] = __builtin_amdgcn_mfma_f32_16x16x32_bf16(af, bf1, acc2[m][1], 0,0,0);
      }
    }
#pragma unroll
    for(int m=0;m<2;m++)
#pragma unroll
    for(int n=0;n<2;n++){
      int col = n0 + n*16 + (lane&15);
#pragma unroll
      for(int i=0;i<4;i++){
        long row = r0 + m*16 + (lane>>4)*4 + i;
        Wh[row*HD+col] = f2b(acc2[m][n][i]);
      }
    }
    // fs/fd: per-wave 32-col partials -> LDS -> block reduce, direct store
    float as0 = a_src[n0 + (lane&15)], as1 = a_src[n0 + 16 + (lane&15)];
    float ad0 = a_dst[n0 + (lane&15)], ad1 = a_dst[n0 + 16 + (lane&15)];
#pragma unroll
    for(int m=0;m<2;m++)
#pragma unroll
    for(int i=0;i<4;i++){
      float ps = acc2[m][0][i]*as0 + acc2[m][1][i]*as1;
      float pd = acc2[m][0][i]*ad0 + acc2[m][1][i]*ad1;
#pragma unroll
      for(int o=1;o<16;o<<=1){ ps += __shfl_xor(ps,o,64); pd += __shfl_xor(pd,o,64); }
      if((lane&15)==0){
        int row = m*16 + (lane>>4)*4 + i;
        fsp[row][w] = ps; fdp[row][w] = pd;
      }
    }
    // whsum column partial (deg-0 fallback)
    float c0=0.f, c1=0.f;
#pragma unroll
    for(int m=0;m<2;m++)
#pragma unroll
    for(int i=0;i<4;i++){ c0 += acc2[m][0][i]; c1 += acc2[m][1][i]; }
    c0 += __shfl_xor(c0,16,64); c0 += __shfl_xor(c0,32,64);
    c1 += __shfl_xor(c1,16,64); c1 += __shfl_xor(c1,32,64);
    if(lane<16){
      atomicAdd(&whsum[n0+lane],    c0);
      atomicAdd(&whsum[n0+16+lane], c1);
    }
    __syncthreads();
    if(t < 32){
      fs[r0+t] = fsp[t][0]+fsp[t][1]+fsp[t][2]+fsp[t][3];
      fd[r0+t] = fdp[t][0]+fdp[t][1]+fdp[t][2]+fdp[t][3];
    }
  } else {
    long r0 = (long)(blockIdx.x - (NWK/32))*32;
    stage_bf16((char*)As[0], h_t  + r0*HD, t);
    stage_bf16((char*)As[1], g_wt + r0*HD, t);
    __syncthreads();
    f32x4 acc[2][2] = {};
    const int slot[2] = {3,5};       // W_task, W_wt
#pragma unroll
    for(int s=0;s<2;s++){
      const __bf16* Wt = (const __bf16*)(Wtb + (size_t)slot[s]*HD*HD);
      char* Ab = (char*)As[s];
#pragma unroll
      for(int kk=0;kk<4;kk++){
        int kb = kk*32 + (lane>>4)*8;
        bf16x8 bf0 = *(const bf16x8*)(Wt + (n0 +      (lane&15))*HD + kb);
        bf16x8 bf1 = *(const bf16x8*)(Wt + (n0 + 16 + (lane&15))*HD + kb);
#pragma unroll
        for(int m=0;m<2;m++){
          int row = m*16 + (lane&15);
          bf16x8 af = *(const bf16x8*)(Ab + ((row*256 + kb*2) ^ ((row&7)<<4)));
          acc[m][0] = __builtin_amdgcn_mfma_f32_16x16x32_bf16(af, bf0, acc[m][0], 0,0,0);
          acc[m][1] = __builtin_amdgcn_mfma_f32_16x16x32_bf16(af, bf1, acc[m][1], 0,0,0);
        }
      }
    }
#pragma unroll
    for(int m=0;m<2;m++)
#pragma unroll
    for(int n=0;n<2;n++){
      int col = n0 + n*16 + (lane&15);
      float bc = b_task[col];
#pragma unroll
      for(int i=0;i<4;i++){
        long row = r0 + m*16 + (lane>>4)*4 + i;
        float vv = acc[m][n][i] + bc;
        vv = vv>0.f ? vv : 0.f;
        vv += b2f(h_t[row*HD+col]);
        out_task[row*HD+col] = vv;
      }
    }
  }
}

// ---- sparse masked attention + ELU + residual -> final_worker
__global__ __launch_bounds__(256) void attn(
    const unsigned short* __restrict__ Wh, const float* __restrict__ fs,
    const float* __restrict__ fd, const int* __restrict__ idx,
    const int* __restrict__ deg, const unsigned short* __restrict__ h_w,
    const float* __restrict__ whsum, float* __restrict__ out){
  __shared__ float pa[4][CWW];
  __shared__ int   pj[4][CWW];
  int w = threadIdx.x>>6, lane = threadIdx.x&63;
  long i = (long)blockIdx.x*4 + w;
  int d = deg[i];
  const int* ji = idx + i*CWW;
  float ax=0.f, ay=0.f;
  if(d > 0){
    float fsi = fs[i];
    float m = -1e30f;
    for(int k=lane;k<d;k+=64){
      int j = ji[k]; pj[w][k] = j;
      float e = fsi + fd[j];
      e = e>0.f ? e : 0.2f*e;
      pa[w][k] = e;
      m = fmaxf(m, e);
    }
    m = wredmax(m);
    float ssum = 0.f;
    for(int k=lane;k<d;k+=64){
      float e = __expf(pa[w][k]-m);
      pa[w][k] = e;
      ssum += e;
    }
    ssum = wredsum(ssum);
    float inv = 1.f/ssum;
    int k=0;
    for(; k+3<d; k+=4){
      float a0=pa[w][k], a1=pa[w][k+1], a2=pa[w][k+2], a3=pa[w][k+3];
      long j0=pj[w][k], j1=pj[w][k+1], j2=pj[w][k+2], j3=pj[w][k+3];
      ushort2 u0 = *(const ushort2*)(Wh + j0*HD + lane*2);
      ushort2 u1 = *(const ushort2*)(Wh + j1*HD + lane*2);
      ushort2 u2 = *(const ushort2*)(Wh + j2*HD + lane*2);
      ushort2 u3 = *(const ushort2*)(Wh + j3*HD + lane*2);
      ax += (a0*b2f(u0.x) + a1*b2f(u1.x)) + (a2*b2f(u2.x) + a3*b2f(u3.x));
      ay += (a0*b2f(u0.y) + a1*b2f(u1.y)) + (a2*b2f(u2.y) + a3*b2f(u3.y));
    }
    for(; k<d; ++k){
      float a0 = pa[w][k];
      long j0 = pj[w][k];
      ushort2 u0 = *(const ushort2*)(Wh + j0*HD + lane*2);
      ax += a0*b2f(u0.x);
      ay += a0*b2f(u0.y);
    }
    ax *= inv; ay *= inv;
  } else {
    ax = whsum[lane*2]   * (1.f/8192.f);
    ay = whsum[lane*2+1] * (1.f/8192.f);
  }
  ushort2 r = *(const ushort2*)(h_w + i*HD + lane*2);
  float2 o;
  o.x = (ax>0.f ? ax : __expf(ax)-1.f) + b2f(r.x);
  o.y = (ay>0.f ? ay : __expf(ay)-1.f) + b2f(r.y);
  *(float2*)(out + i*HD + lane*2) = o;
}

extern "C" void kernel_launch(void* const* d_in, const int* in_sizes, int n_in,
                              void* d_out, int out_size, void* d_ws, size_t ws_size,
                              hipStream_t stream){
  const float* Xw       = (const float*)d_in[0];
  const float* Xt       = (const float*)d_in[1];
  const float* WW       = (const float*)d_in[2];
  const float* WT       = (const float*)d_in[3];
  const float* Wp_w     = (const float*)d_in[4];
  const float* bp_w     = (const float*)d_in[5];
  const float* Wp_t     = (const float*)d_in[6];
  const float* bp_t     = (const float*)d_in[7];
  const float* W_worker = (const float*)d_in[8];
  const float* b_worker = (const float*)d_in[9];
  const float* W_task   = (const float*)d_in[10];
  const float* b_task   = (const float*)d_in[11];
  const float* W_ww     = (const float*)d_in[12];
  const float* W_wt     = (const float*)d_in[13];
  const float* W_tw     = (const float*)d_in[14];
  const float* W_igat   = (const float*)d_in[15];
  const float* a_src    = (const float*)d_in[16];
  const float* a_dst    = (const float*)d_in[17];
  float* out = (float*)d_out;

  char* p = (char*)d_ws;
  auto alloc = [&](size_t bytes)->char*{
    char* r = p; p += (bytes + 255) & ~(size_t)255; return r;
  };
  int* ww_idx  = (int*)alloc((size_t)NWK*CWW*4);
  int* wt_idx  = (int*)alloc((size_t)NWK*CWTR*4);
  int* wt_cidx = (int*)alloc((size_t)NTK*CWTC*4);
  int* ww_deg  = (int*)alloc(NWK*4);
  int* wt_deg  = (int*)alloc(NWK*4);
  int*   fill  = (int*)alloc(NTK*4);
  float* whsum = (float*)alloc(512);
  float* fs    = (float*)alloc(NWK*4);
  float* fd    = (float*)alloc(NWK*4);
  unsigned short* h_w  = (unsigned short*)alloc((size_t)NWK*HD*2);
  unsigned short* h_t  = (unsigned short*)alloc((size_t)NTK*HD*2);
  unsigned short* g_ww = (unsigned short*)alloc((size_t)NWK*HD*2);
  unsigned short* g_tw = (unsigned short*)alloc((size_t)NWK*HD*2);
  unsigned short* g_wt = (unsigned short*)alloc((size_t)NTK*HD*2);
  unsigned short* Wh   = (unsigned short*)alloc((size_t)NWK*HD*2);
  unsigned short* Wtb  = (unsigned short*)alloc((size_t)8*HD*HD*2);

  prepw<<<32,256,0,stream>>>(Wp_w, Wp_t, W_worker, W_task, W_ww, W_wt, W_tw, W_igat,
                             Wtb, fill, whsum);
  build_all<<<NWK/2,256,0,stream>>>(WW, WT, ww_idx, ww_deg, wt_idx, wt_deg, wt_cidx, fill);
  kproj<<<NWK/32 + NTK/32,256,0,stream>>>(Xw, Xt, Wtb, bp_w, bp_t, h_w, h_t);
  agg<<<(NWK+NTK)/4,256,0,stream>>>(h_w, h_t, ww_idx, ww_deg, wt_idx, wt_deg,
                                    wt_cidx, fill, g_ww, g_tw, g_wt);
  krgcn<<<NWK/32 + NTK/32,256,0,stream>>>(h_w, h_t, g_ww, g_tw, g_wt, Wtb,
                                          b_worker, b_task, a_src, a_dst,
                                          Wh, fs, fd, whsum, out + (size_t)NWK*HD);
  attn<<<NWK/4,256,0,stream>>>(Wh, fs, fd, ww_idx, ww_deg, h_w, whsum, out);
}

// Round 7
// 166.474 us; speedup vs baseline: 2.2544x; 1.0361x over previous
//
#include <hip/hip_runtime.h>

static constexpr int NWK  = 8192;
static constexpr int NTK  = 4096;
static constexpr int HD   = 128;
static constexpr int CWW  = 256;   // cap ww row degree (mean 82, max~125)
static constexpr int CWTR = 128;   // cap wt row degree (mean 41)
static constexpr int CWTC = 256;   // cap wt col degree (mean 82)
static constexpr int QCW  = 128;   // per-wave quarter cap, ww (mean 20, max~45)
static constexpr int QCT  = 64;    // per-wave quarter cap, wt (mean 10, max~30)

typedef float  f32x4  __attribute__((ext_vector_type(4)));
typedef __bf16 bf16x8 __attribute__((ext_vector_type(8)));

__device__ __forceinline__ float b2f(unsigned short u){
  unsigned int x = ((unsigned int)u) << 16;
  return __builtin_bit_cast(float, x);
}
__device__ __forceinline__ unsigned short f2b(float x){
  return __builtin_bit_cast(unsigned short, (__bf16)x);
}
__device__ __forceinline__ float wredmax(float v){
#pragma unroll
  for(int o=32;o;o>>=1) v = fmaxf(v, __shfl_xor(v,o,64));
  return v;
}
__device__ __forceinline__ float wredsum(float v){
#pragma unroll
  for(int o=32;o;o>>=1) v += __shfl_xor(v,o,64);
  return v;
}

// ---- weight prep (W [in][out] f32 -> Wt [out][in] bf16) + zero fill/whsum
__global__ __launch_bounds__(256) void prepw(
    const float* s0,const float* s1,const float* s2,const float* s3,
    const float* s4,const float* s5,const float* s6,const float* s7,
    unsigned short* dst, int* fill, float* whsum){
  if(blockIdx.x < 16) fill[blockIdx.x*256 + threadIdx.x] = 0;
  if(blockIdx.x == 16 && threadIdx.x < 128) whsum[threadIdx.x] = 0.f;
  const float* srcs[8] = {s0,s1,s2,s3,s4,s5,s6,s7};
  int mat = blockIdx.x>>2, sl = blockIdx.x&3;
  const float* s = srcs[mat];
  unsigned short* d = dst + (size_t)mat*HD*HD;
  for(int idx=threadIdx.x + sl*4096; idx<(sl+1)*4096; idx+=256){
    int k = idx>>7, n = idx&127;
    d[n*HD+k] = f2b(s[idx]);
  }
}

// ---- one 256-col chunk: ballot compaction into LDS (no VMEM writes)
template<int CAP>
__device__ __forceinline__ void scan_chunk(
    float4 x, int c0base, int& base, int* __restrict__ sbuf, int lane){
  bool p0=x.x>0.f, p1=x.y>0.f, p2=x.z>0.f, p3=x.w>0.f;
  unsigned long long b0=__ballot(p0),b1=__ballot(p1),b2=__ballot(p2),b3=__ballot(p3);
  unsigned long long below = (1ull<<lane)-1ull;
  int pos = base + __popcll(b0&below)+__popcll(b1&below)+__popcll(b2&below)+__popcll(b3&below);
  int c0 = c0base + lane*4;
  if(p0){ if(pos<CAP) sbuf[pos]=c0;   pos++; }
  if(p1){ if(pos<CAP) sbuf[pos]=c0+1; pos++; }
  if(p2){ if(pos<CAP) sbuf[pos]=c0+2; pos++; }
  if(p3){ if(pos<CAP) sbuf[pos]=c0+3; pos++; }
  base += __popcll(b0)+__popcll(b1)+__popcll(b2)+__popcll(b3);
}

// ---- block-per-row adjacency scan: wave w owns quarter [w*Q,(w+1)*Q),
//      ALL quarter loads issued upfront (one latency exposure per wave),
//      LDS compaction, single barrier, prefix-merge of 4 sorted quarter lists.
template<int NCH, int QCAP, bool SCATTER>
__device__ __forceinline__ void scan_row_block(
    const float* __restrict__ adj, long row, int ncols, int cap,
    int* __restrict__ orow, int* __restrict__ deg,
    int* __restrict__ cidx, int* __restrict__ fill, int ccap,
    int lane, int w, int (* __restrict__ sbuf)[QCW], int* __restrict__ cnts){
  const int Q = NCH*256;
  const float4* src = (const float4*)(adj + row*(long)ncols) + ((w*Q)>>2);
  float4 v[NCH];
#pragma unroll
  for(int c=0;c<NCH;c++) v[c] = src[c*64 + lane];     // full burst: NCH KB/wave in flight
  int base = 0;
#pragma unroll
  for(int c=0;c<NCH;c++)
    scan_chunk<QCAP>(v[c], w*Q + c*256, base, sbuf[w], lane);
  int cnt = base<QCAP ? base : QCAP;
  if(lane==0) cnts[w] = cnt;
  __syncthreads();
  int c0=cnts[0], c1=cnts[1], c2=cnts[2], c3=cnts[3];
  int off = (w>0?c0:0) + (w>1?c1:0) + (w>2?c2:0);
  int tot = c0+c1+c2+c3;
  if(w==0 && lane==0) deg[row] = tot<cap ? tot : cap;
  for(int k=lane; k<cnt; k+=64){
    int p = off+k;
    if(p<cap) orow[p] = sbuf[w][k];
  }
  if(SCATTER){
    for(int k=lane; k<cnt; k+=64){
      int task = sbuf[w][k];
      int pp = atomicAdd(&fill[task], 1);
      if(pp < ccap) cidx[(long)task*ccap + pp] = (int)row;
    }
  }
}

__global__ __launch_bounds__(256) void build_all(
    const float* __restrict__ WW, const float* __restrict__ WT,
    int* __restrict__ ww_idx, int* __restrict__ ww_deg,
    int* __restrict__ wt_idx, int* __restrict__ wt_deg,
    int* __restrict__ cidx, int* __restrict__ fill){
  __shared__ int sbuf[4][QCW];       // 2 KB per-wave compaction buffers
  __shared__ int cnts[4];
  int lane = threadIdx.x&63, w = threadIdx.x>>6;
  int b = blockIdx.x;
  if(b < NWK){
    long row = b;
    scan_row_block<8,QCW,false>(WW, row, NWK, CWW, ww_idx + row*CWW, ww_deg,
                                nullptr, nullptr, 0, lane, w, sbuf, cnts);
  } else {
    long row = b - NWK;              // wt has NWK rows (one per worker)!
    scan_row_block<4,QCT,true>(WT, row, NTK, CWTR, wt_idx + row*CWTR, wt_deg,
                               cidx, fill, CWTC, lane, w, sbuf, cnts);
  }
}

// ---- fused projections: h = relu(X@Wp + b), output bf16
__global__ __launch_bounds__(256) void kproj(
    const float* __restrict__ Xw, const float* __restrict__ Xt,
    const unsigned short* __restrict__ Wtb,
    const float* __restrict__ bp_w, const float* __restrict__ bp_t,
    unsigned short* __restrict__ h_w, unsigned short* __restrict__ h_t){
  bool task = blockIdx.x >= (NWK/32);
  const float* X = task ? Xt : Xw;
  const __bf16* Wt = (const __bf16*)(Wtb + (size_t)(task?1:0)*HD*HD);
  const float* bias = task ? bp_t : bp_w;
  unsigned short* H = task ? h_t : h_w;
  long r0 = (long)(task ? blockIdx.x-(NWK/32) : blockIdx.x)*32;

  __shared__ __bf16 As[32*HD];
  char* Ab = (char*)As;
  int t = threadIdx.x, lane = t&63, w = t>>6;
  const float4* A4 = (const float4*)(X + r0*HD);
#pragma unroll
  for(int i=0;i<4;i++){
    int id = t + i*256;
    float4 v = A4[id];
    int row = id>>5, c4 = id&31;
    int byte = row*256 + c4*8;
    ushort4 b; b.x=f2b(v.x); b.y=f2b(v.y); b.z=f2b(v.z); b.w=f2b(v.w);
    *(ushort4*)(Ab + (byte ^ ((row&7)<<4))) = b;
  }
  __syncthreads();
  f32x4 acc[2][2] = {};
  int n0 = w*32;
#pragma unroll
  for(int kk=0;kk<4;kk++){
    int kb = kk*32 + (lane>>4)*8;
    bf16x8 bf0 = *(const bf16x8*)(Wt + (n0 +      (lane&15))*HD + kb);
    bf16x8 bf1 = *(const bf16x8*)(Wt + (n0 + 16 + (lane&15))*HD + kb);
#pragma unroll
    for(int m=0;m<2;m++){
      int row = m*16 + (lane&15);
      bf16x8 af = *(const bf16x8*)(Ab + ((row*256 + kb*2) ^ ((row&7)<<4)));
      acc[m][0] = __builtin_amdgcn_mfma_f32_16x16x32_bf16(af, bf0, acc[m][0], 0,0,0);
      acc[m][1] = __builtin_amdgcn_mfma_f32_16x16x32_bf16(af, bf1, acc[m][1], 0,0,0);
    }
  }
#pragma unroll
  for(int m=0;m<2;m++)
#pragma unroll
  for(int n=0;n<2;n++){
    int col = n0 + n*16 + (lane&15);
    float bc = bias[col];
#pragma unroll
    for(int i=0;i<4;i++){
      long row = r0 + m*16 + (lane>>4)*4 + i;
      float vv = acc[m][n][i] + bc;
      vv = vv>0.f ? vv : 0.f;
      H[row*HD+col] = f2b(vv);
    }
  }
}

// ---- gather-sum of a bf16 [*,128] table over an index list (4-wide unrolled)
__device__ __forceinline__ void gather_sum(
    const unsigned short* __restrict__ tab, const int* __restrict__ ji, int d,
    int lane, float& ax, float& ay){
  int k=0;
  for(; k+3<d; k+=4){
    long j0=ji[k], j1=ji[k+1], j2=ji[k+2], j3=ji[k+3];
    ushort2 u0 = *(const ushort2*)(tab + j0*HD + lane*2);
    ushort2 u1 = *(const ushort2*)(tab + j1*HD + lane*2);
    ushort2 u2 = *(const ushort2*)(tab + j2*HD + lane*2);
    ushort2 u3 = *(const ushort2*)(tab + j3*HD + lane*2);
    ax += (b2f(u0.x)+b2f(u1.x)) + (b2f(u2.x)+b2f(u3.x));
    ay += (b2f(u0.y)+b2f(u1.y)) + (b2f(u2.y)+b2f(u3.y));
  }
  for(; k<d; ++k){
    long j0=ji[k];
    ushort2 u0 = *(const ushort2*)(tab + j0*HD + lane*2);
    ax += b2f(u0.x); ay += b2f(u0.y);
  }
}

// ---- aggregate raw h
__global__ __launch_bounds__(256) void agg(
    const unsigned short* __restrict__ h_w, const unsigned short* __restrict__ h_t,
    const int* __restrict__ wwidx, const int* __restrict__ wwdeg,
    const int* __restrict__ wtidx, const int* __restrict__ wtdeg,
    const int* __restrict__ cidx,  const int* __restrict__ fill,
    unsigned short* __restrict__ g_ww, unsigned short* __restrict__ g_tw,
    unsigned short* __restrict__ g_wt){
  int w = threadIdx.x>>6, lane = threadIdx.x&63;
  long i = (long)blockIdx.x*4 + w;
  if(i < NWK){
    float ax=0.f, ay=0.f;
    gather_sum(h_w, wwidx + i*CWW, wwdeg[i], lane, ax, ay);
    ushort2 o; o.x=f2b(ax); o.y=f2b(ay);
    *(ushort2*)(g_ww + i*HD + lane*2) = o;
    ax=0.f; ay=0.f;
    gather_sum(h_t, wtidx + i*CWTR, wtdeg[i], lane, ax, ay);
    o.x=f2b(ax); o.y=f2b(ay);
    *(ushort2*)(g_tw + i*HD + lane*2) = o;
  } else {
    long tt = i - NWK;
    float ax=0.f, ay=0.f;
    int d = fill[tt]; if(d>CWTC) d=CWTC;
    gather_sum(h_w, cidx + tt*CWTC, d, lane, ax, ay);
    ushort2 o; o.x=f2b(ax); o.y=f2b(ay);
    *(ushort2*)(g_wt + tt*HD + lane*2) = o;
  }
}

// ---- stage a 32x128 bf16 tile into swizzled LDS
__device__ __forceinline__ void stage_bf16(char* Ab, const unsigned short* src, int t){
#pragma unroll
  for(int i=0;i<2;i++){
    int id = t + i*256;
    int row = id>>4, c8 = id&15;
    bf16x8 v = *(const bf16x8*)(src + row*HD + c8*8);
    int byte = row*256 + c8*16;
    *(bf16x8*)(Ab + (byte ^ ((row&7)<<4))) = v;
  }
}

// ---- RGCN + IGAT fused
__global__ __launch_bounds__(256) void krgcn(
    const unsigned short* __restrict__ h_w, const unsigned short* __restrict__ h_t,
    const unsigned short* __restrict__ g_ww, const unsigned short* __restrict__ g_tw,
    const unsigned short* __restrict__ g_wt,
    const unsigned short* __restrict__ Wtb,
    const float* __restrict__ b_worker, const float* __restrict__ b_task,
    const float* __restrict__ a_src, const float* __restrict__ a_dst,
    unsigned short* __restrict__ Wh, float* __restrict__ fs, float* __restrict__ fd,
    float* __restrict__ whsum, float* __restrict__ out_task){
  __shared__ __bf16 As[3][32*HD];    // 24 KB
  __shared__ __bf16 Hs[32*HD];       // 8 KB
  __shared__ float fsp[32][4], fdp[32][4];
  int t = threadIdx.x, lane = t&63, w = t>>6, n0 = w*32;
  bool task = blockIdx.x >= (NWK/32);

  if(!task){
    long r0 = (long)blockIdx.x*32;
    stage_bf16((char*)As[0], h_w  + r0*HD, t);
    stage_bf16((char*)As[1], g_ww + r0*HD, t);
    stage_bf16((char*)As[2], g_tw + r0*HD, t);
    __syncthreads();
    f32x4 acc[2][2] = {};
    const int slot[3] = {2,4,6};     // W_worker, W_ww, W_tw
#pragma unroll
    for(int s=0;s<3;s++){
      const __bf16* Wt = (const __bf16*)(Wtb + (size_t)slot[s]*HD*HD);
      char* Ab = (char*)As[s];
#pragma unroll
      for(int kk=0;kk<4;kk++){
        int kb = kk*32 + (lane>>4)*8;
        bf16x8 bf0 = *(const bf16x8*)(Wt + (n0 +      (lane&15))*HD + kb);
        bf16x8 bf1 = *(const bf16x8*)(Wt + (n0 + 16 + (lane&15))*HD + kb);
#pragma unroll
        for(int m=0;m<2;m++){
          int row = m*16 + (lane&15);
          bf16x8 af = *(const bf16x8*)(Ab + ((row*256 + kb*2) ^ ((row&7)<<4)));
          acc[m][0] = __builtin_amdgcn_mfma_f32_16x16x32_bf16(af, bf0, acc[m][0], 0,0,0);
          acc[m][1] = __builtin_amdgcn_mfma_f32_16x16x32_bf16(af, bf1, acc[m][1], 0,0,0);
        }
      }
    }
    char* HsB = (char*)Hs;
#pragma unroll
    for(int m=0;m<2;m++)
#pragma unroll
    for(int n=0;n<2;n++){
      int col = n0 + n*16 + (lane&15);
      float bc = b_worker[col];
#pragma unroll
      for(int i=0;i<4;i++){
        int row = m*16 + (lane>>4)*4 + i;
        float vv = acc[m][n][i] + bc;
        vv = vv>0.f ? vv : 0.f;
        int byte = row*256 + col*2;
        *(__bf16*)(HsB + (byte ^ ((row&7)<<4))) = (__bf16)vv;
      }
    }
    __syncthreads();
    // stage2: Wh = hwr @ W_igat
    f32x4 acc2[2][2] = {};
    const __bf16* Wt7 = (const __bf16*)(Wtb + (size_t)7*HD*HD);
#pragma unroll
    for(int kk=0;kk<4;kk++){
      int kb = kk*32 + (lane>>4)*8;
      bf16x8 bf0 = *(const bf16x8*)(Wt7 + (n0 +      (lane&15))*HD + kb);
      bf16x8 bf1 = *(const bf16x8*)(Wt7 + (n0 + 16 + (lane&15))*HD + kb);
#pragma unroll
      for(int m=0;m<2;m++){
        int row = m*16 + (lane&15);
        bf16x8 af = *(const bf16x8*)(HsB + ((row*256 + kb*2) ^ ((row&7)<<4)));
        acc2[m][0] = __builtin_amdgcn_mfma_f32_16x16x32_bf16(af, bf0, acc2[m][0], 0,0,0);
        acc2[m][1] = __builtin_amdgcn_mfma_f32_16x16x32_bf16(af, bf1, acc2[m][1], 0,0,0);
      }
    }
#pragma unroll
    for(int m=0;m<2;m++)
#pragma unroll
    for(int n=0;n<2;n++){
      int col = n0 + n*16 + (lane&15);
#pragma unroll
      for(int i=0;i<4;i++){
        long row = r0 + m*16 + (lane>>4)*4 + i;
        Wh[row*HD+col] = f2b(acc2[m][n][i]);
      }
    }
    // fs/fd: per-wave 32-col partials -> LDS -> block reduce, direct store
    float as0 = a_src[n0 + (lane&15)], as1 = a_src[n0 + 16 + (lane&15)];
    float ad0 = a_dst[n0 + (lane&15)], ad1 = a_dst[n0 + 16 + (lane&15)];
#pragma unroll
    for(int m=0;m<2;m++)
#pragma unroll
    for(int i=0;i<4;i++){
      float ps = acc2[m][0][i]*as0 + acc2[m][1][i]*as1;
      float pd = acc2[m][0][i]*ad0 + acc2[m][1][i]*ad1;
#pragma unroll
      for(int o=1;o<16;o<<=1){ ps += __shfl_xor(ps,o,64); pd += __shfl_xor(pd,o,64); }
      if((lane&15)==0){
        int row = m*16 + (lane>>4)*4 + i;
        fsp[row][w] = ps; fdp[row][w] = pd;
      }
    }
    // whsum column partial (deg-0 fallback)
    float c0=0.f, c1=0.f;
#pragma unroll
    for(int m=0;m<2;m++)
#pragma unroll
    for(int i=0;i<4;i++){ c0 += acc2[m][0][i]; c1 += acc2[m][1][i]; }
    c0 += __shfl_xor(c0,16,64); c0 += __shfl_xor(c0,32,64);
    c1 += __shfl_xor(c1,16,64); c1 += __shfl_xor(c1,32,64);
    if(lane<16){
      atomicAdd(&whsum[n0+lane],    c0);
      atomicAdd(&whsum[n0+16+lane], c1);
    }
    __syncthreads();
    if(t < 32){
      fs[r0+t] = fsp[t][0]+fsp[t][1]+fsp[t][2]+fsp[t][3];
      fd[r0+t] = fdp[t][0]+fdp[t][1]+fdp[t][2]+fdp[t][3];
    }
  } else {
    long r0 = (long)(blockIdx.x - (NWK/32))*32;
    stage_bf16((char*)As[0], h_t  + r0*HD, t);
    stage_bf16((char*)As[1], g_wt + r0*HD, t);
    __syncthreads();
    f32x4 acc[2][2] = {};
    const int slot[2] = {3,5};       // W_task, W_wt
#pragma unroll
    for(int s=0;s<2;s++){
      const __bf16* Wt = (const __bf16*)(Wtb + (size_t)slot[s]*HD*HD);
      char* Ab = (char*)As[s];
#pragma unroll
      for(int kk=0;kk<4;kk++){
        int kb = kk*32 + (lane>>4)*8;
        bf16x8 bf0 = *(const bf16x8*)(Wt + (n0 +      (lane&15))*HD + kb);
        bf16x8 bf1 = *(const bf16x8*)(Wt + (n0 + 16 + (lane&15))*HD + kb);
#pragma unroll
        for(int m=0;m<2;m++){
          int row = m*16 + (lane&15);
          bf16x8 af = *(const bf16x8*)(Ab + ((row*256 + kb*2) ^ ((row&7)<<4)));
          acc[m][0] = __builtin_amdgcn_mfma_f32_16x16x32_bf16(af, bf0, acc[m][0], 0,0,0);
          acc[m][1] = __builtin_amdgcn_mfma_f32_16x16x32_bf16(af, bf1, acc[m][1], 0,0,0);
        }
      }
    }
#pragma unroll
    for(int m=0;m<2;m++)
#pragma unroll
    for(int n=0;n<2;n++){
      int col = n0 + n*16 + (lane&15);
      float bc = b_task[col];
#pragma unroll
      for(int i=0;i<4;i++){
        long row = r0 + m*16 + (lane>>4)*4 + i;
        float vv = acc[m][n][i] + bc;
        vv = vv>0.f ? vv : 0.f;
        vv += b2f(h_t[row*HD+col]);
        out_task[row*HD+col] = vv;
      }
    }
  }
}

// ---- sparse masked attention + ELU + residual -> final_worker
__global__ __launch_bounds__(256) void attn(
    const unsigned short* __restrict__ Wh, const float* __restrict__ fs,
    const float* __restrict__ fd, const int* __restrict__ idx,
    const int* __restrict__ deg, const unsigned short* __restrict__ h_w,
    const float* __restrict__ whsum, float* __restrict__ out){
  __shared__ float pa[4][CWW];
  __shared__ int   pj[4][CWW];
  int w = threadIdx.x>>6, lane = threadIdx.x&63;
  long i = (long)blockIdx.x*4 + w;
  int d = deg[i];
  const int* ji = idx + i*CWW;
  float ax=0.f, ay=0.f;
  if(d > 0){
    float fsi = fs[i];
    float m = -1e30f;
    for(int k=lane;k<d;k+=64){
      int j = ji[k]; pj[w][k] = j;
      float e = fsi + fd[j];
      e = e>0.f ? e : 0.2f*e;
      pa[w][k] = e;
      m = fmaxf(m, e);
    }
    m = wredmax(m);
    float ssum = 0.f;
    for(int k=lane;k<d;k+=64){
      float e = __expf(pa[w][k]-m);
      pa[w][k] = e;
      ssum += e;
    }
    ssum = wredsum(ssum);
    float inv = 1.f/ssum;
    int k=0;
    for(; k+3<d; k+=4){
      float a0=pa[w][k], a1=pa[w][k+1], a2=pa[w][k+2], a3=pa[w][k+3];
      long j0=pj[w][k], j1=pj[w][k+1], j2=pj[w][k+2], j3=pj[w][k+3];
      ushort2 u0 = *(const ushort2*)(Wh + j0*HD + lane*2);
      ushort2 u1 = *(const ushort2*)(Wh + j1*HD + lane*2);
      ushort2 u2 = *(const ushort2*)(Wh + j2*HD + lane*2);
      ushort2 u3 = *(const ushort2*)(Wh + j3*HD + lane*2);
      ax += (a0*b2f(u0.x) + a1*b2f(u1.x)) + (a2*b2f(u2.x) + a3*b2f(u3.x));
      ay += (a0*b2f(u0.y) + a1*b2f(u1.y)) + (a2*b2f(u2.y) + a3*b2f(u3.y));
    }
    for(; k<d; ++k){
      float a0 = pa[w][k];
      long j0 = pj[w][k];
      ushort2 u0 = *(const ushort2*)(Wh + j0*HD + lane*2);
      ax += a0*b2f(u0.x);
      ay += a0*b2f(u0.y);
    }
    ax *= inv; ay *= inv;
  } else {
    ax = whsum[lane*2]   * (1.f/8192.f);
    ay = whsum[lane*2+1] * (1.f/8192.f);
  }
  ushort2 r = *(const ushort2*)(h_w + i*HD + lane*2);
  float2 o;
  o.x = (ax>0.f ? ax : __expf(ax)-1.f) + b2f(r.x);
  o.y = (ay>0.f ? ay : __expf(ay)-1.f) + b2f(r.y);
  *(float2*)(out + i*HD + lane*2) = o;
}

extern "C" void kernel_launch(void* const* d_in, const int* in_sizes, int n_in,
                              void* d_out, int out_size, void* d_ws, size_t ws_size,
                              hipStream_t stream){
  const float* Xw       = (const float*)d_in[0];
  const float* Xt       = (const float*)d_in[1];
  const float* WW       = (const float*)d_in[2];
  const float* WT       = (const float*)d_in[3];
  const float* Wp_w     = (const float*)d_in[4];
  const float* bp_w     = (const float*)d_in[5];
  const float* Wp_t     = (const float*)d_in[6];
  const float* bp_t     = (const float*)d_in[7];
  const float* W_worker = (const float*)d_in[8];
  const float* b_worker = (const float*)d_in[9];
  const float* W_task   = (const float*)d_in[10];
  const float* b_task   = (const float*)d_in[11];
  const float* W_ww     = (const float*)d_in[12];
  const float* W_wt     = (const float*)d_in[13];
  const float* W_tw     = (const float*)d_in[14];
  const float* W_igat   = (const float*)d_in[15];
  const float* a_src    = (const float*)d_in[16];
  const float* a_dst    = (const float*)d_in[17];
  float* out = (float*)d_out;

  char* p = (char*)d_ws;
  auto alloc = [&](size_t bytes)->char*{
    char* r = p; p += (bytes + 255) & ~(size_t)255; return r;
  };
  int* ww_idx  = (int*)alloc((size_t)NWK*CWW*4);
  int* wt_idx  = (int*)alloc((size_t)NWK*CWTR*4);
  int* wt_cidx = (int*)alloc((size_t)NTK*CWTC*4);
  int* ww_deg  = (int*)alloc(NWK*4);
  int* wt_deg  = (int*)alloc(NWK*4);
  int*   fill  = (int*)alloc(NTK*4);
  float* whsum = (float*)alloc(512);
  float* fs    = (float*)alloc(NWK*4);
  float* fd    = (float*)alloc(NWK*4);
  unsigned short* h_w  = (unsigned short*)alloc((size_t)NWK*HD*2);
  unsigned short* h_t  = (unsigned short*)alloc((size_t)NTK*HD*2);
  unsigned short* g_ww = (unsigned short*)alloc((size_t)NWK*HD*2);
  unsigned short* g_tw = (unsigned short*)alloc((size_t)NWK*HD*2);
  unsigned short* g_wt = (unsigned short*)alloc((size_t)NTK*HD*2);
  unsigned short* Wh   = (unsigned short*)alloc((size_t)NWK*HD*2);
  unsigned short* Wtb  = (unsigned short*)alloc((size_t)8*HD*HD*2);

  prepw<<<32,256,0,stream>>>(Wp_w, Wp_t, W_worker, W_task, W_ww, W_wt, W_tw, W_igat,
                             Wtb, fill, whsum);
  build_all<<<NWK*2,256,0,stream>>>(WW, WT, ww_idx, ww_deg, wt_idx, wt_deg,
                                    wt_cidx, fill);
  kproj<<<NWK/32 + NTK/32,256,0,stream>>>(Xw, Xt, Wtb, bp_w, bp_t, h_w, h_t);
  agg<<<(NWK+NTK)/4,256,0,stream>>>(h_w, h_t, ww_idx, ww_deg, wt_idx, wt_deg,
                                    wt_cidx, fill, g_ww, g_tw, g_wt);
  krgcn<<<NWK/32 + NTK/32,256,0,stream>>>(h_w, h_t, g_ww, g_tw, g_wt, Wtb,
                                          b_worker, b_task, a_src, a_dst,
                                          Wh, fs, fd, whsum, out + (size_t)NWK*HD);
  attn<<<NWK/4,256,0,stream>>>(Wh, fs, fd, ww_idx, ww_deg, h_w, whsum, out);
}